// Round 1
// baseline (2788.839 us; speedup 1.0000x reference)
//
#include <hip/hip_runtime.h>
#include <math.h>

#define BB 16
#define CC 512
#define LL 1024
#define NCONV 4
#define KW 7
#define NH 8
#define DH 64

// ---------------------------------------------------------------- pos enc
__global__ __launch_bounds__(256) void pos_enc_kernel(
    const float* __restrict__ x, float* __restrict__ out)
{
    int idx = blockIdx.x * 256 + threadIdx.x;          // B*C*L total
    int l = idx & (LL - 1);
    int c = (idx >> 10) & (CC - 1);
    const float log_inc = 0.03611898185f;              // log(10000)/255
    int cc = (c < CC / 2) ? c : c - CC / 2;
    float inv = expf(-log_inc * (float)cc);
    float ph = (float)l * inv;
    float sig = (c < CC / 2) ? sinf(ph) : cosf(ph);
    out[idx] = x[idx] + sig;
}

// ---------------------------------------------------------------- layernorm over channels (fused stats+apply)
// grid: (L/64, B), block 256.  thread = (lx 0..63, cg 0..3)
__global__ __launch_bounds__(256) void ln_ch_kernel(
    const float* __restrict__ x, const float* __restrict__ gam,
    const float* __restrict__ bet, float* __restrict__ out)
{
    int b = blockIdx.y;
    int l0 = blockIdx.x * 64;
    int lx = threadIdx.x & 63;
    int cg = threadIdx.x >> 6;        // 0..3
    const float* xb = x + (size_t)b * CC * LL + l0 + lx;

    float sum = 0.f, sumsq = 0.f;
    for (int c = cg * 128; c < cg * 128 + 128; ++c) {
        float v = xb[(size_t)c * LL];
        sum += v; sumsq += v * v;
    }
    __shared__ float s_sum[4][64], s_sq[4][64];
    __shared__ float s_mean[64], s_rstd[64];
    s_sum[cg][lx] = sum; s_sq[cg][lx] = sumsq;
    __syncthreads();
    if (cg == 0) {
        float tot  = s_sum[0][lx] + s_sum[1][lx] + s_sum[2][lx] + s_sum[3][lx];
        float tot2 = s_sq[0][lx]  + s_sq[1][lx]  + s_sq[2][lx]  + s_sq[3][lx];
        float mean = tot * (1.0f / CC);
        float var  = tot2 * (1.0f / CC) - mean * mean;
        s_mean[lx] = mean;
        s_rstd[lx] = rsqrtf(var + 1e-5f);
    }
    __syncthreads();
    float mean = s_mean[lx], rstd = s_rstd[lx];
    float* ob = out + (size_t)b * CC * LL + l0 + lx;
    for (int c = cg * 128; c < cg * 128 + 128; ++c) {
        float v = xb[(size_t)c * LL];
        ob[(size_t)c * LL] = (v - mean) * rstd * gam[c] + bet[c];
    }
}

// ---------------------------------------------------------------- depthwise conv K=7, pad 3
__global__ __launch_bounds__(256) void dwconv_kernel(
    const float* __restrict__ x, const float* __restrict__ w, float* __restrict__ out)
{
    int idx = blockIdx.x * 256 + threadIdx.x;
    int l = idx & (LL - 1);
    int bc = idx >> 10;
    int c = bc & (CC - 1);
    const float* wr = w + c * KW;
    const float* xr = x + (size_t)bc * LL;
    float acc = 0.f;
    #pragma unroll
    for (int k = 0; k < KW; ++k) {
        int ll = l + k - 3;
        float v = (ll >= 0 && ll < LL) ? xr[ll] : 0.0f;
        acc += wr[k] * v;
    }
    out[idx] = acc;
}

// ---------------------------------------------------------------- generic fp32 GEMM  Y[b] = act(W @ X[b] * scale + bias) + res
// W: (M,Kc) row-major.  X: (B,Kc,L).  Y/res: (B,M,L).  128x128 tile, 8x8/thread.
__global__ __launch_bounds__(256) void gemm_kernel(
    const float* __restrict__ Wm, const float* __restrict__ X,
    float* __restrict__ Y, const float* __restrict__ bias,
    const float* __restrict__ res, const int M, const int Kc,
    const int relu, const float scale)
{
    const int b  = blockIdx.z;
    const int l0 = blockIdx.x * 128;
    const int o0 = blockIdx.y * 128;
    const float* Xb = X + (size_t)b * Kc * LL;
    __shared__ __align__(16) float Wl[16 * 132];
    __shared__ __align__(16) float Xl[16 * 132];
    const int tid = threadIdx.x;
    const int tx = tid & 15, ty = tid >> 4;
    float acc[8][8] = {};

    for (int k0 = 0; k0 < Kc; k0 += 16) {
        {
            int kk = tid & 15, oo = tid >> 4;            // 16 kk x 16 oo
            #pragma unroll
            for (int p = 0; p < 8; ++p)
                Wl[kk * 132 + oo + p * 16] =
                    Wm[(size_t)(o0 + oo + p * 16) * Kc + k0 + kk];
            int lc = tid & 127, kr = tid >> 7;           // 128 lc x 2 kr
            #pragma unroll
            for (int p = 0; p < 8; ++p)
                Xl[(kr + p * 2) * 132 + lc] =
                    Xb[(size_t)(k0 + kr + p * 2) * LL + l0 + lc];
        }
        __syncthreads();
        #pragma unroll
        for (int kk = 0; kk < 16; ++kk) {
            const float4* ap = (const float4*)(Wl + kk * 132 + ty * 8);
            const float4* bp = (const float4*)(Xl + kk * 132 + tx * 8);
            float4 A0 = ap[0], A1 = ap[1], B0 = bp[0], B1 = bp[1];
            float a[8]  = {A0.x, A0.y, A0.z, A0.w, A1.x, A1.y, A1.z, A1.w};
            float bb[8] = {B0.x, B0.y, B0.z, B0.w, B1.x, B1.y, B1.z, B1.w};
            #pragma unroll
            for (int r = 0; r < 8; ++r)
                #pragma unroll
                for (int j = 0; j < 8; ++j)
                    acc[r][j] += a[r] * bb[j];
        }
        __syncthreads();
    }

    const size_t ybase = (size_t)b * M * LL;
    #pragma unroll
    for (int r = 0; r < 8; ++r) {
        int o = o0 + ty * 8 + r;
        float bv = bias ? bias[o] : 0.f;
        #pragma unroll
        for (int j0 = 0; j0 < 8; j0 += 4) {
            size_t idx = ybase + (size_t)o * LL + l0 + tx * 8 + j0;
            float4 v4;
            float v0 = acc[r][j0 + 0] * scale + bv;
            float v1 = acc[r][j0 + 1] * scale + bv;
            float v2 = acc[r][j0 + 2] * scale + bv;
            float v3 = acc[r][j0 + 3] * scale + bv;
            if (relu) {
                v0 = fmaxf(v0, 0.f); v1 = fmaxf(v1, 0.f);
                v2 = fmaxf(v2, 0.f); v3 = fmaxf(v3, 0.f);
            }
            if (res) {
                float4 r4 = *(const float4*)(res + idx);
                v0 += r4.x; v1 += r4.y; v2 += r4.z; v3 += r4.w;
            }
            v4.x = v0; v4.y = v1; v4.z = v2; v4.w = v3;
            *(float4*)(Y + idx) = v4;
        }
    }
}

// ---------------------------------------------------------------- flash attention, fp32
// grid (L/32, H, B), block 256. thread: qr = tid>>3 (0..31), mg = tid&7.
// q already scaled by DH^-0.5. outp += attention (residual in place).
__global__ __launch_bounds__(256) void attn_kernel(
    const float* __restrict__ qb, const float* __restrict__ kb,
    const float* __restrict__ vb, const int* __restrict__ maskp,
    float* __restrict__ outp)
{
    const int b   = blockIdx.z;
    const int hh  = blockIdx.y;
    const int ql0 = blockIdx.x * 32;
    const int tid = threadIdx.x;
    const int qr  = tid >> 3;
    const int mg  = tid & 7;

    __shared__ __align__(16) float smem[(32 + 64 + 64) * 68];
    float* Qs = smem;               // [32][68]  (ql, d)
    float* Ks = smem + 32 * 68;     // [64][68]  (d, m)
    float* Vs = Ks + 64 * 68;       // [64][68]  (d, m)

    const size_t base = (size_t)(b * CC + hh * DH) * LL;

    {   // stage Q
        int lq = tid & 31, dg = tid >> 5;     // dg 0..7
        #pragma unroll
        for (int dd = 0; dd < 8; ++dd) {
            int d = dg * 8 + dd;
            Qs[lq * 68 + d] = qb[base + (size_t)d * LL + ql0 + lq];
        }
    }

    float m_run = -INFINITY, l_run = 0.f;
    float oacc[64];
    #pragma unroll
    for (int d = 0; d < 64; ++d) oacc[d] = 0.f;

    for (int m0 = 0; m0 < LL; m0 += 64) {
        __syncthreads();
        {   // stage K,V tiles  [d][m]
            int mm = tid & 63, dg = tid >> 6;   // dg 0..3
            #pragma unroll
            for (int p = 0; p < 16; ++p) {
                int d = dg * 16 + p;
                Ks[d * 68 + mm] = kb[base + (size_t)d * LL + m0 + mm];
                Vs[d * 68 + mm] = vb[base + (size_t)d * LL + m0 + mm];
            }
        }
        __syncthreads();

        float s[8] = {0.f, 0.f, 0.f, 0.f, 0.f, 0.f, 0.f, 0.f};
        for (int d = 0; d < 64; ++d) {
            float qv = Qs[qr * 68 + d];
            const float4* kp = (const float4*)(Ks + d * 68 + mg * 8);
            float4 k0 = kp[0], k1 = kp[1];
            s[0] += qv * k0.x; s[1] += qv * k0.y; s[2] += qv * k0.z; s[3] += qv * k0.w;
            s[4] += qv * k1.x; s[5] += qv * k1.y; s[6] += qv * k1.z; s[7] += qv * k1.w;
        }

        float tmax = -INFINITY;
        #pragma unroll
        for (int j = 0; j < 8; ++j) {
            float mf = (float)maskp[b * LL + m0 + mg * 8 + j];
            s[j] += -1e30f * (1.0f - mf);
            tmax = fmaxf(tmax, s[j]);
        }
        float nm = fmaxf(m_run, tmax);
        float corr = __expf(m_run - nm);
        float w[8]; float ws = 0.f;
        #pragma unroll
        for (int j = 0; j < 8; ++j) { w[j] = __expf(s[j] - nm); ws += w[j]; }
        l_run = l_run * corr + ws;
        m_run = nm;
        #pragma unroll
        for (int d = 0; d < 64; ++d) oacc[d] *= corr;
        #pragma unroll
        for (int d = 0; d < 64; ++d) {
            const float4* vp = (const float4*)(Vs + d * 68 + mg * 8);
            float4 v0 = vp[0], v1 = vp[1];
            oacc[d] += w[0] * v0.x + w[1] * v0.y + w[2] * v0.z + w[3] * v0.w
                     + w[4] * v1.x + w[5] * v1.y + w[6] * v1.z + w[7] * v1.w;
        }
    }

    // butterfly merge across the 8 column-groups (lanes qr*8+mg, same wave)
    #pragma unroll
    for (int off = 1; off < 8; off <<= 1) {
        float m2 = __shfl_xor(m_run, off);
        float l2 = __shfl_xor(l_run, off);
        float nm = fmaxf(m_run, m2);
        float f1 = __expf(m_run - nm), f2 = __expf(m2 - nm);
        l_run = l_run * f1 + l2 * f2;
        #pragma unroll
        for (int d = 0; d < 64; ++d) {
            float o2 = __shfl_xor(oacc[d], off);
            oacc[d] = oacc[d] * f1 + o2 * f2;
        }
        m_run = nm;
    }

    float inv_l = 1.0f / l_run;
    #pragma unroll
    for (int j = 0; j < 8; ++j) {
        int d = mg * 8 + j;
        size_t idx = base + (size_t)d * LL + ql0 + qr;
        outp[idx] = outp[idx] + oacc[d] * inv_l;
    }
}

// ---------------------------------------------------------------- launch
extern "C" void kernel_launch(void* const* d_in, const int* in_sizes, int n_in,
                              void* d_out, int out_size, void* d_ws, size_t ws_size,
                              hipStream_t stream)
{
    const float* inputx  = (const float*)d_in[0];
    const int*   mask    = (const int*)  d_in[1];
    const float* ncs     = (const float*)d_in[4];
    const float* ncb     = (const float*)d_in[5];
    const float* dw_w    = (const float*)d_in[6];
    const float* pw_w    = (const float*)d_in[7];
    const float* pw_b    = (const float*)d_in[8];
    const float* ln1_s   = (const float*)d_in[9];
    const float* ln1_b   = (const float*)d_in[10];
    const float* ln2_s   = (const float*)d_in[11];
    const float* ln2_b   = (const float*)d_in[12];
    const float* w_kv    = (const float*)d_in[13];
    const float* w_q     = (const float*)d_in[14];
    const float* ffn1_w  = (const float*)d_in[15];
    const float* ffn1_b  = (const float*)d_in[16];
    const float* ffn2_w  = (const float*)d_in[17];
    const float* ffn2_b  = (const float*)d_in[18];

    float* ws = (float*)d_ws;
    const size_t NT = (size_t)BB * CC * LL;   // 8,388,608 floats
    float* result = ws;
    float* hbuf   = ws + NT;
    float* h2buf  = ws + 2 * NT;   // also q
    float* kbuf   = ws + 3 * NT;
    float* vbuf   = ws + 4 * NT;

    const int nelem = BB * CC * LL;
    dim3 blk(256);
    dim3 ggrid(LL / 128, CC / 128, BB);
    dim3 lgrid(LL / 64, BB);

    pos_enc_kernel<<<nelem / 256, blk, 0, stream>>>(inputx, result);

    for (int i = 0; i < NCONV; ++i) {
        ln_ch_kernel<<<lgrid, blk, 0, stream>>>(result, ncs + i * CC, ncb + i * CC, hbuf);
        dwconv_kernel<<<nelem / 256, blk, 0, stream>>>(hbuf, dw_w + i * CC * KW, h2buf);
        gemm_kernel<<<ggrid, blk, 0, stream>>>(pw_w + (size_t)i * CC * CC, h2buf, result,
                                               pw_b + i * CC, result, CC, CC, 1, 1.0f);
    }

    // attention
    ln_ch_kernel<<<lgrid, blk, 0, stream>>>(result, ln1_s, ln1_b, hbuf);
    gemm_kernel<<<ggrid, blk, 0, stream>>>(w_kv,            hbuf, kbuf, nullptr, nullptr, CC, CC, 0, 1.0f);
    gemm_kernel<<<ggrid, blk, 0, stream>>>(w_kv + CC * CC,  hbuf, vbuf, nullptr, nullptr, CC, CC, 0, 1.0f);
    gemm_kernel<<<ggrid, blk, 0, stream>>>(w_q,             hbuf, h2buf, nullptr, nullptr, CC, CC, 0, 0.125f);
    attn_kernel<<<dim3(LL / 32, NH, BB), blk, 0, stream>>>(h2buf, kbuf, vbuf, mask, result);

    // ffn
    ln_ch_kernel<<<lgrid, blk, 0, stream>>>(result, ln2_s, ln2_b, hbuf);
    gemm_kernel<<<ggrid, blk, 0, stream>>>(ffn1_w, hbuf, h2buf, ffn1_b, nullptr, CC, CC, 1, 1.0f);
    gemm_kernel<<<ggrid, blk, 0, stream>>>(ffn2_w, h2buf, (float*)d_out, ffn2_b, result, CC, CC, 0, 1.0f);
}

// Round 2
// 2051.460 us; speedup vs baseline: 1.3594x; 1.3594x over previous
//
#include <hip/hip_runtime.h>
#include <math.h>

#define BB 16
#define CC 512
#define LL 1024
#define NCONV 4
#define KW 7
#define NH 8
#define DH 64

// ---------------------------------------------------------------- pos enc
__global__ __launch_bounds__(256) void pos_enc_kernel(
    const float* __restrict__ x, float* __restrict__ out)
{
    int idx = blockIdx.x * 256 + threadIdx.x;          // B*C*L total
    int l = idx & (LL - 1);
    int c = (idx >> 10) & (CC - 1);
    const float log_inc = 0.03611898185f;              // log(10000)/255
    int cc = (c < CC / 2) ? c : c - CC / 2;
    float inv = expf(-log_inc * (float)cc);
    float ph = (float)l * inv;
    float sig = (c < CC / 2) ? sinf(ph) : cosf(ph);
    out[idx] = x[idx] + sig;
}

// ---------------------------------------------------------------- layernorm over channels (fused stats+apply)
// grid: (L/64, B), block 256.  thread = (lx 0..63, cg 0..3)
__global__ __launch_bounds__(256) void ln_ch_kernel(
    const float* __restrict__ x, const float* __restrict__ gam,
    const float* __restrict__ bet, float* __restrict__ out)
{
    int b = blockIdx.y;
    int l0 = blockIdx.x * 64;
    int lx = threadIdx.x & 63;
    int cg = threadIdx.x >> 6;        // 0..3
    const float* xb = x + (size_t)b * CC * LL + l0 + lx;

    float sum = 0.f, sumsq = 0.f;
    for (int c = cg * 128; c < cg * 128 + 128; ++c) {
        float v = xb[(size_t)c * LL];
        sum += v; sumsq += v * v;
    }
    __shared__ float s_sum[4][64], s_sq[4][64];
    __shared__ float s_mean[64], s_rstd[64];
    s_sum[cg][lx] = sum; s_sq[cg][lx] = sumsq;
    __syncthreads();
    if (cg == 0) {
        float tot  = s_sum[0][lx] + s_sum[1][lx] + s_sum[2][lx] + s_sum[3][lx];
        float tot2 = s_sq[0][lx]  + s_sq[1][lx]  + s_sq[2][lx]  + s_sq[3][lx];
        float mean = tot * (1.0f / CC);
        float var  = tot2 * (1.0f / CC) - mean * mean;
        s_mean[lx] = mean;
        s_rstd[lx] = rsqrtf(var + 1e-5f);
    }
    __syncthreads();
    float mean = s_mean[lx], rstd = s_rstd[lx];
    float* ob = out + (size_t)b * CC * LL + l0 + lx;
    for (int c = cg * 128; c < cg * 128 + 128; ++c) {
        float v = xb[(size_t)c * LL];
        ob[(size_t)c * LL] = (v - mean) * rstd * gam[c] + bet[c];
    }
}

// ---------------------------------------------------------------- depthwise conv K=7, pad 3
__global__ __launch_bounds__(256) void dwconv_kernel(
    const float* __restrict__ x, const float* __restrict__ w, float* __restrict__ out)
{
    int idx = blockIdx.x * 256 + threadIdx.x;
    int l = idx & (LL - 1);
    int bc = idx >> 10;
    int c = bc & (CC - 1);
    const float* wr = w + c * KW;
    const float* xr = x + (size_t)bc * LL;
    float acc = 0.f;
    #pragma unroll
    for (int k = 0; k < KW; ++k) {
        int ll = l + k - 3;
        float v = (ll >= 0 && ll < LL) ? xr[ll] : 0.0f;
        acc += wr[k] * v;
    }
    out[idx] = acc;
}

// ---------------------------------------------------------------- generic fp32 GEMM  Y[b] = act(W @ X[b] * scale + bias) + res
// W: (M,Kc) row-major.  X: (B,Kc,L).  Y/res: (B,M,L).  128x128 tile, 8x8/thread.
__global__ __launch_bounds__(256) void gemm_kernel(
    const float* __restrict__ Wm, const float* __restrict__ X,
    float* __restrict__ Y, const float* __restrict__ bias,
    const float* __restrict__ res, const int M, const int Kc,
    const int relu, const float scale)
{
    const int b  = blockIdx.z;
    const int l0 = blockIdx.x * 128;
    const int o0 = blockIdx.y * 128;
    const float* Xb = X + (size_t)b * Kc * LL;
    __shared__ __align__(16) float Wl[16 * 132];
    __shared__ __align__(16) float Xl[16 * 132];
    const int tid = threadIdx.x;
    const int tx = tid & 15, ty = tid >> 4;
    float acc[8][8] = {};

    for (int k0 = 0; k0 < Kc; k0 += 16) {
        {
            int kk = tid & 15, oo = tid >> 4;            // 16 kk x 16 oo
            #pragma unroll
            for (int p = 0; p < 8; ++p)
                Wl[kk * 132 + oo + p * 16] =
                    Wm[(size_t)(o0 + oo + p * 16) * Kc + k0 + kk];
            int lc = tid & 127, kr = tid >> 7;           // 128 lc x 2 kr
            #pragma unroll
            for (int p = 0; p < 8; ++p)
                Xl[(kr + p * 2) * 132 + lc] =
                    Xb[(size_t)(k0 + kr + p * 2) * LL + l0 + lc];
        }
        __syncthreads();
        #pragma unroll
        for (int kk = 0; kk < 16; ++kk) {
            const float4* ap = (const float4*)(Wl + kk * 132 + ty * 8);
            const float4* bp = (const float4*)(Xl + kk * 132 + tx * 8);
            float4 A0 = ap[0], A1 = ap[1], B0 = bp[0], B1 = bp[1];
            float a[8]  = {A0.x, A0.y, A0.z, A0.w, A1.x, A1.y, A1.z, A1.w};
            float bb[8] = {B0.x, B0.y, B0.z, B0.w, B1.x, B1.y, B1.z, B1.w};
            #pragma unroll
            for (int r = 0; r < 8; ++r)
                #pragma unroll
                for (int j = 0; j < 8; ++j)
                    acc[r][j] += a[r] * bb[j];
        }
        __syncthreads();
    }

    const size_t ybase = (size_t)b * M * LL;
    #pragma unroll
    for (int r = 0; r < 8; ++r) {
        int o = o0 + ty * 8 + r;
        float bv = bias ? bias[o] : 0.f;
        #pragma unroll
        for (int j0 = 0; j0 < 8; j0 += 4) {
            size_t idx = ybase + (size_t)o * LL + l0 + tx * 8 + j0;
            float4 v4;
            float v0 = acc[r][j0 + 0] * scale + bv;
            float v1 = acc[r][j0 + 1] * scale + bv;
            float v2 = acc[r][j0 + 2] * scale + bv;
            float v3 = acc[r][j0 + 3] * scale + bv;
            if (relu) {
                v0 = fmaxf(v0, 0.f); v1 = fmaxf(v1, 0.f);
                v2 = fmaxf(v2, 0.f); v3 = fmaxf(v3, 0.f);
            }
            if (res) {
                float4 r4 = *(const float4*)(res + idx);
                v0 += r4.x; v1 += r4.y; v2 += r4.z; v3 += r4.w;
            }
            v4.x = v0; v4.y = v1; v4.z = v2; v4.w = v3;
            *(float4*)(Y + idx) = v4;
        }
    }
}

// ---------------------------------------------------------------- flash attention, fp32, two-phase (no register spills)
// grid (L/64, H, B), block 256. Thread t: r = t>>2 (q-row 0..63),
// phase1: mg = t&3 -> 8 scores (m = mg*8..+7); phase2: dg = t&3 -> oacc[16]
// (d = dg*16..+15). Same r both phases => softmax state stays in registers.
// q already scaled by DH^-0.5. outp += attention (residual in place).
__global__ __launch_bounds__(256) void attn_kernel(
    const float* __restrict__ qb, const float* __restrict__ kb,
    const float* __restrict__ vb, const int* __restrict__ maskp,
    float* __restrict__ outp)
{
    const int b   = blockIdx.z;
    const int hh  = blockIdx.y;
    const int ql0 = blockIdx.x * 64;
    const int tid = threadIdx.x;
    const int r   = tid >> 2;      // q-row within tile
    const int mg  = tid & 3;       // m-group / d-group

    __shared__ __align__(16) float Qs[64 * 68];   // [q][d]
    __shared__ __align__(16) float Ks[64 * 36];   // [d][m]
    __shared__ __align__(16) float Vs[32 * 68];   // [m][d]
    __shared__ __align__(16) float Pl[64 * 36];   // [q][m]

    const size_t base = (size_t)(b * CC + hh * DH) * LL;

    {   // stage Q  (once per block; 8-way write conflict, 16 instrs, negligible)
        int lq = tid & 63, dgx = tid >> 6;
        #pragma unroll
        for (int p = 0; p < 16; ++p) {
            int d = dgx * 16 + p;
            Qs[lq * 68 + d] = qb[base + (size_t)d * LL + ql0 + lq];
        }
    }

    float m_run = -INFINITY, l_run = 0.f;
    float oacc[16];
    #pragma unroll
    for (int i = 0; i < 16; ++i) oacc[i] = 0.f;

    for (int m0 = 0; m0 < LL; m0 += 32) {
        __syncthreads();   // prev phase-2 done (and Q staged, iter 0)
        {   // stage K  [d][m]: mm = tid&31, dk = tid>>5 (8 d each)
            int mm = tid & 31, dk = tid >> 5;
            #pragma unroll
            for (int p = 0; p < 8; ++p) {
                int d = dk * 8 + p;
                Ks[d * 36 + mm] = kb[base + (size_t)d * LL + m0 + mm];
            }
        }
        {   // stage V transposed [m][d]: float4 over m from global, scalar LDS writes (2-way, free)
            int mq = tid & 7, dv = tid >> 3;   // dv 0..31
            #pragma unroll
            for (int p = 0; p < 2; ++p) {
                int d = dv + 32 * p;
                float4 v4 = *(const float4*)(vb + base + (size_t)d * LL + m0 + mq * 4);
                Vs[(mq * 4 + 0) * 68 + d] = v4.x;
                Vs[(mq * 4 + 1) * 68 + d] = v4.y;
                Vs[(mq * 4 + 2) * 68 + d] = v4.z;
                Vs[(mq * 4 + 3) * 68 + d] = v4.w;
            }
        }
        __syncthreads();

        // ---- phase 1: scores s[8] for (row r, m = mg*8..+7)
        float s[8] = {0.f, 0.f, 0.f, 0.f, 0.f, 0.f, 0.f, 0.f};
        #pragma unroll 4
        for (int d4 = 0; d4 < 16; ++d4) {
            float4 q4 = *(const float4*)(Qs + r * 68 + d4 * 4);
            #pragma unroll
            for (int mi = 0; mi < 4; ++mi) {
                float q = (&q4.x)[mi];
                const float4* kp = (const float4*)(Ks + (d4 * 4 + mi) * 36 + mg * 8);
                float4 k0 = kp[0], k1 = kp[1];
                s[0] += q * k0.x; s[1] += q * k0.y; s[2] += q * k0.z; s[3] += q * k0.w;
                s[4] += q * k1.x; s[5] += q * k1.y; s[6] += q * k1.z; s[7] += q * k1.w;
            }
        }
        float tmax = -INFINITY;
        #pragma unroll
        for (int j = 0; j < 8; ++j) {
            float mf = (float)maskp[b * LL + m0 + mg * 8 + j];
            s[j] += -1e30f * (1.0f - mf);
            tmax = fmaxf(tmax, s[j]);
        }
        tmax = fmaxf(tmax, __shfl_xor(tmax, 1));    // merge across 4 same-row lanes
        tmax = fmaxf(tmax, __shfl_xor(tmax, 2));
        float nm = fmaxf(m_run, tmax);
        float corr = __expf(m_run - nm);
        float ws = 0.f;
        #pragma unroll
        for (int j = 0; j < 8; ++j) { s[j] = __expf(s[j] - nm); ws += s[j]; }
        ws += __shfl_xor(ws, 1);
        ws += __shfl_xor(ws, 2);
        l_run = l_run * corr + ws;
        m_run = nm;
        *(float4*)(Pl + r * 36 + mg * 8)     = make_float4(s[0], s[1], s[2], s[3]);
        *(float4*)(Pl + r * 36 + mg * 8 + 4) = make_float4(s[4], s[5], s[6], s[7]);
        __syncthreads();

        // ---- phase 2: oacc[16] for (row r, d = mg*16..+15)
        #pragma unroll
        for (int i = 0; i < 16; ++i) oacc[i] *= corr;
        #pragma unroll 2
        for (int m4 = 0; m4 < 8; ++m4) {
            float4 p4 = *(const float4*)(Pl + r * 36 + m4 * 4);
            #pragma unroll
            for (int mi = 0; mi < 4; ++mi) {
                float pv = (&p4.x)[mi];
                const float4* vp = (const float4*)(Vs + (m4 * 4 + mi) * 68 + mg * 16);
                float4 v0 = vp[0], v1 = vp[1], v2 = vp[2], v3 = vp[3];
                oacc[0]  += pv * v0.x; oacc[1]  += pv * v0.y; oacc[2]  += pv * v0.z; oacc[3]  += pv * v0.w;
                oacc[4]  += pv * v1.x; oacc[5]  += pv * v1.y; oacc[6]  += pv * v1.z; oacc[7]  += pv * v1.w;
                oacc[8]  += pv * v2.x; oacc[9]  += pv * v2.y; oacc[10] += pv * v2.z; oacc[11] += pv * v2.w;
                oacc[12] += pv * v3.x; oacc[13] += pv * v3.y; oacc[14] += pv * v3.z; oacc[15] += pv * v3.w;
            }
        }
    }

    float inv_l = 1.0f / l_run;
    #pragma unroll
    for (int dd = 0; dd < 16; ++dd) {
        int d = mg * 16 + dd;
        size_t idx = base + (size_t)d * LL + ql0 + r;
        outp[idx] = outp[idx] + oacc[dd] * inv_l;
    }
}

// ---------------------------------------------------------------- launch
extern "C" void kernel_launch(void* const* d_in, const int* in_sizes, int n_in,
                              void* d_out, int out_size, void* d_ws, size_t ws_size,
                              hipStream_t stream)
{
    const float* inputx  = (const float*)d_in[0];
    const int*   mask    = (const int*)  d_in[1];
    const float* ncs     = (const float*)d_in[4];
    const float* ncb     = (const float*)d_in[5];
    const float* dw_w    = (const float*)d_in[6];
    const float* pw_w    = (const float*)d_in[7];
    const float* pw_b    = (const float*)d_in[8];
    const float* ln1_s   = (const float*)d_in[9];
    const float* ln1_b   = (const float*)d_in[10];
    const float* ln2_s   = (const float*)d_in[11];
    const float* ln2_b   = (const float*)d_in[12];
    const float* w_kv    = (const float*)d_in[13];
    const float* w_q     = (const float*)d_in[14];
    const float* ffn1_w  = (const float*)d_in[15];
    const float* ffn1_b  = (const float*)d_in[16];
    const float* ffn2_w  = (const float*)d_in[17];
    const float* ffn2_b  = (const float*)d_in[18];

    float* ws = (float*)d_ws;
    const size_t NT = (size_t)BB * CC * LL;   // 8,388,608 floats
    float* result = ws;
    float* hbuf   = ws + NT;
    float* h2buf  = ws + 2 * NT;   // also q
    float* kbuf   = ws + 3 * NT;
    float* vbuf   = ws + 4 * NT;

    const int nelem = BB * CC * LL;
    dim3 blk(256);
    dim3 ggrid(LL / 128, CC / 128, BB);
    dim3 lgrid(LL / 64, BB);

    pos_enc_kernel<<<nelem / 256, blk, 0, stream>>>(inputx, result);

    for (int i = 0; i < NCONV; ++i) {
        ln_ch_kernel<<<lgrid, blk, 0, stream>>>(result, ncs + i * CC, ncb + i * CC, hbuf);
        dwconv_kernel<<<nelem / 256, blk, 0, stream>>>(hbuf, dw_w + i * CC * KW, h2buf);
        gemm_kernel<<<ggrid, blk, 0, stream>>>(pw_w + (size_t)i * CC * CC, h2buf, result,
                                               pw_b + i * CC, result, CC, CC, 1, 1.0f);
    }

    // attention
    ln_ch_kernel<<<lgrid, blk, 0, stream>>>(result, ln1_s, ln1_b, hbuf);
    gemm_kernel<<<ggrid, blk, 0, stream>>>(w_kv,            hbuf, kbuf, nullptr, nullptr, CC, CC, 0, 1.0f);
    gemm_kernel<<<ggrid, blk, 0, stream>>>(w_kv + CC * CC,  hbuf, vbuf, nullptr, nullptr, CC, CC, 0, 1.0f);
    gemm_kernel<<<ggrid, blk, 0, stream>>>(w_q,             hbuf, h2buf, nullptr, nullptr, CC, CC, 0, 0.125f);
    attn_kernel<<<dim3(LL / 64, NH, BB), blk, 0, stream>>>(h2buf, kbuf, vbuf, mask, result);

    // ffn
    ln_ch_kernel<<<lgrid, blk, 0, stream>>>(result, ln2_s, ln2_b, hbuf);
    gemm_kernel<<<ggrid, blk, 0, stream>>>(ffn1_w, hbuf, h2buf, ffn1_b, nullptr, CC, CC, 1, 1.0f);
    gemm_kernel<<<ggrid, blk, 0, stream>>>(ffn2_w, h2buf, (float*)d_out, ffn2_b, result, CC, CC, 0, 1.0f);
}

// Round 3
// 1411.975 us; speedup vs baseline: 1.9751x; 1.4529x over previous
//
#include <hip/hip_runtime.h>
#include <math.h>

#define BB 16
#define CC 512
#define LL 1024
#define NCONV 4
#define KW 7
#define NH 8
#define DH 64

typedef short short8 __attribute__((ext_vector_type(8)));
typedef float f32x4  __attribute__((ext_vector_type(4)));

// ---------------------------------------------------------------- pos enc
__global__ __launch_bounds__(256) void pos_enc_kernel(
    const float* __restrict__ x, float* __restrict__ out)
{
    int idx = blockIdx.x * 256 + threadIdx.x;          // B*C*L total
    int l = idx & (LL - 1);
    int c = (idx >> 10) & (CC - 1);
    const float log_inc = 0.03611898185f;              // log(10000)/255
    int cc = (c < CC / 2) ? c : c - CC / 2;
    float inv = expf(-log_inc * (float)cc);
    float ph = (float)l * inv;
    float sig = (c < CC / 2) ? sinf(ph) : cosf(ph);
    out[idx] = x[idx] + sig;
}

// ---------------------------------------------------------------- layernorm over channels (fused stats+apply)
__global__ __launch_bounds__(256) void ln_ch_kernel(
    const float* __restrict__ x, const float* __restrict__ gam,
    const float* __restrict__ bet, float* __restrict__ out)
{
    int b = blockIdx.y;
    int l0 = blockIdx.x * 64;
    int lx = threadIdx.x & 63;
    int cg = threadIdx.x >> 6;        // 0..3
    const float* xb = x + (size_t)b * CC * LL + l0 + lx;

    float sum = 0.f, sumsq = 0.f;
    for (int c = cg * 128; c < cg * 128 + 128; ++c) {
        float v = xb[(size_t)c * LL];
        sum += v; sumsq += v * v;
    }
    __shared__ float s_sum[4][64], s_sq[4][64];
    __shared__ float s_mean[64], s_rstd[64];
    s_sum[cg][lx] = sum; s_sq[cg][lx] = sumsq;
    __syncthreads();
    if (cg == 0) {
        float tot  = s_sum[0][lx] + s_sum[1][lx] + s_sum[2][lx] + s_sum[3][lx];
        float tot2 = s_sq[0][lx]  + s_sq[1][lx]  + s_sq[2][lx]  + s_sq[3][lx];
        float mean = tot * (1.0f / CC);
        float var  = tot2 * (1.0f / CC) - mean * mean;
        s_mean[lx] = mean;
        s_rstd[lx] = rsqrtf(var + 1e-5f);
    }
    __syncthreads();
    float mean = s_mean[lx], rstd = s_rstd[lx];
    float* ob = out + (size_t)b * CC * LL + l0 + lx;
    for (int c = cg * 128; c < cg * 128 + 128; ++c) {
        float v = xb[(size_t)c * LL];
        ob[(size_t)c * LL] = (v - mean) * rstd * gam[c] + bet[c];
    }
}

// ---------------------------------------------------------------- depthwise conv K=7, pad 3
__global__ __launch_bounds__(256) void dwconv_kernel(
    const float* __restrict__ x, const float* __restrict__ w, float* __restrict__ out)
{
    int idx = blockIdx.x * 256 + threadIdx.x;
    int l = idx & (LL - 1);
    int bc = idx >> 10;
    int c = bc & (CC - 1);
    const float* wr = w + c * KW;
    const float* xr = x + (size_t)bc * LL;
    float acc = 0.f;
    #pragma unroll
    for (int k = 0; k < KW; ++k) {
        int ll = l + k - 3;
        float v = (ll >= 0 && ll < LL) ? xr[ll] : 0.0f;
        acc += wr[k] * v;
    }
    out[idx] = acc;
}

// ---------------------------------------------------------------- bf16 MFMA GEMM
// Y[b] = act(W @ X[b] * scale + bias) + res.  W: (M,Kc) fp32 row-major,
// X: (B,Kc,L) fp32.  In-kernel fp32->bf16 conversion during LDS staging.
// 128x128 tile, BK=32, 4 waves (2x2), each wave 64x64 via 4x4 mfma 16x16x32.
// Wl[m][k] stride 40 bf16 (b128 frag reads 2-way = free).
// Xl[n][k] stride 40 bf16 staged transposed (packed-pair ds_write_b32).
__global__ __launch_bounds__(256) void gemm_mfma_kernel(
    const float* __restrict__ Wm, const float* __restrict__ X,
    float* __restrict__ Y, const float* __restrict__ bias,
    const float* __restrict__ res, const int M, const int Kc,
    const int relu, const float scale)
{
    const int b  = blockIdx.z;
    const int l0 = blockIdx.x * 128;
    const int o0 = blockIdx.y * 128;
    const float* Xb = X + (size_t)b * Kc * LL;

    __shared__ __bf16 Wl[128 * 40];
    __shared__ __bf16 Xl[128 * 40];

    const int tid  = threadIdx.x;
    const int wave = tid >> 6;
    const int lane = tid & 63;
    const int wm = wave >> 1, wn = wave & 1;
    const int ln = lane & 15, kq = lane >> 4;

    f32x4 acc[4][4] = {};

    // staging thread mappings
    const int sm    = tid >> 1;       // W row 0..127 (2 threads/row)
    const int shalf = tid & 1;        // which 16-k half
    const int sn    = tid & 127;      // X col n (coalesced lanes)
    const int skg   = tid >> 7;       // k-pair group 0/1

    for (int k0 = 0; k0 < Kc; k0 += 32) {
        __syncthreads();               // previous iter's frag reads done
        // ---- stage W tile: Wl[m][k]
        {
            const float* src = Wm + (size_t)(o0 + sm) * Kc + k0 + shalf * 16;
            float4 f0 = *(const float4*)(src + 0);
            float4 f1 = *(const float4*)(src + 4);
            float4 f2 = *(const float4*)(src + 8);
            float4 f3 = *(const float4*)(src + 12);
            union { __bf16 h[16]; short8 s[2]; } u;
            u.h[0]=(__bf16)f0.x;  u.h[1]=(__bf16)f0.y;  u.h[2]=(__bf16)f0.z;  u.h[3]=(__bf16)f0.w;
            u.h[4]=(__bf16)f1.x;  u.h[5]=(__bf16)f1.y;  u.h[6]=(__bf16)f1.z;  u.h[7]=(__bf16)f1.w;
            u.h[8]=(__bf16)f2.x;  u.h[9]=(__bf16)f2.y;  u.h[10]=(__bf16)f2.z; u.h[11]=(__bf16)f2.w;
            u.h[12]=(__bf16)f3.x; u.h[13]=(__bf16)f3.y; u.h[14]=(__bf16)f3.z; u.h[15]=(__bf16)f3.w;
            short8* dst = (short8*)(Wl + sm * 40 + shalf * 16);
            dst[0] = u.s[0];
            dst[1] = u.s[1];
        }
        // ---- stage X tile transposed: Xl[n][k]
        {
            #pragma unroll
            for (int j = 0; j < 8; ++j) {
                int kp = skg * 8 + j;                   // k-pair index 0..15
                float e0 = Xb[(size_t)(k0 + 2 * kp    ) * LL + l0 + sn];
                float e1 = Xb[(size_t)(k0 + 2 * kp + 1) * LL + l0 + sn];
                union { __bf16 h[2]; unsigned u; } pk;
                pk.h[0] = (__bf16)e0; pk.h[1] = (__bf16)e1;
                *(unsigned*)(Xl + sn * 40 + 2 * kp) = pk.u;
            }
        }
        __syncthreads();
        // ---- fragments + 16 MFMAs
        short8 af[4], bfr[4];
        #pragma unroll
        for (int mi = 0; mi < 4; ++mi)
            af[mi] = *(const short8*)(Wl + (wm * 64 + mi * 16 + ln) * 40 + kq * 8);
        #pragma unroll
        for (int ni = 0; ni < 4; ++ni)
            bfr[ni] = *(const short8*)(Xl + (wn * 64 + ni * 16 + ln) * 40 + kq * 8);
        #pragma unroll
        for (int mi = 0; mi < 4; ++mi)
            #pragma unroll
            for (int ni = 0; ni < 4; ++ni)
                acc[mi][ni] = __builtin_amdgcn_mfma_f32_16x16x32_bf16(
                    af[mi], bfr[ni], acc[mi][ni], 0, 0, 0);
    }

    // ---- epilogue: D col = lane&15 (n), row = quad*4 + reg (m)
    const size_t ybase = (size_t)b * M * LL;
    #pragma unroll
    for (int mi = 0; mi < 4; ++mi) {
        const int mbase = o0 + wm * 64 + mi * 16 + kq * 4;
        #pragma unroll
        for (int ni = 0; ni < 4; ++ni) {
            const int n = l0 + wn * 64 + ni * 16 + ln;
            #pragma unroll
            for (int i = 0; i < 4; ++i) {
                const int m = mbase + i;
                float v = acc[mi][ni][i] * scale;
                if (bias) v += bias[m];
                if (relu) v = fmaxf(v, 0.f);
                size_t idx = ybase + (size_t)m * LL + n;
                if (res) v += res[idx];
                Y[idx] = v;
            }
        }
    }
}

// ---------------------------------------------------------------- flash attention, fp32, two-phase (no register spills)
__global__ __launch_bounds__(256) void attn_kernel(
    const float* __restrict__ qb, const float* __restrict__ kb,
    const float* __restrict__ vb, const int* __restrict__ maskp,
    float* __restrict__ outp)
{
    const int b   = blockIdx.z;
    const int hh  = blockIdx.y;
    const int ql0 = blockIdx.x * 64;
    const int tid = threadIdx.x;
    const int r   = tid >> 2;      // q-row within tile
    const int mg  = tid & 3;       // m-group / d-group

    __shared__ __align__(16) float Qs[64 * 68];   // [q][d]
    __shared__ __align__(16) float Ks[64 * 36];   // [d][m]
    __shared__ __align__(16) float Vs[32 * 68];   // [m][d]
    __shared__ __align__(16) float Pl[64 * 36];   // [q][m]

    const size_t base = (size_t)(b * CC + hh * DH) * LL;

    {   // stage Q
        int lq = tid & 63, dgx = tid >> 6;
        #pragma unroll
        for (int p = 0; p < 16; ++p) {
            int d = dgx * 16 + p;
            Qs[lq * 68 + d] = qb[base + (size_t)d * LL + ql0 + lq];
        }
    }

    float m_run = -INFINITY, l_run = 0.f;
    float oacc[16];
    #pragma unroll
    for (int i = 0; i < 16; ++i) oacc[i] = 0.f;

    for (int m0 = 0; m0 < LL; m0 += 32) {
        __syncthreads();
        {   // stage K  [d][m]
            int mm = tid & 31, dk = tid >> 5;
            #pragma unroll
            for (int p = 0; p < 8; ++p) {
                int d = dk * 8 + p;
                Ks[d * 36 + mm] = kb[base + (size_t)d * LL + m0 + mm];
            }
        }
        {   // stage V transposed [m][d]
            int mq = tid & 7, dv = tid >> 3;
            #pragma unroll
            for (int p = 0; p < 2; ++p) {
                int d = dv + 32 * p;
                float4 v4 = *(const float4*)(vb + base + (size_t)d * LL + m0 + mq * 4);
                Vs[(mq * 4 + 0) * 68 + d] = v4.x;
                Vs[(mq * 4 + 1) * 68 + d] = v4.y;
                Vs[(mq * 4 + 2) * 68 + d] = v4.z;
                Vs[(mq * 4 + 3) * 68 + d] = v4.w;
            }
        }
        __syncthreads();

        // ---- phase 1: scores s[8] for (row r, m = mg*8..+7)
        float s[8] = {0.f, 0.f, 0.f, 0.f, 0.f, 0.f, 0.f, 0.f};
        #pragma unroll 4
        for (int d4 = 0; d4 < 16; ++d4) {
            float4 q4 = *(const float4*)(Qs + r * 68 + d4 * 4);
            #pragma unroll
            for (int mi = 0; mi < 4; ++mi) {
                float q = (&q4.x)[mi];
                const float4* kp = (const float4*)(Ks + (d4 * 4 + mi) * 36 + mg * 8);
                float4 k0 = kp[0], k1 = kp[1];
                s[0] += q * k0.x; s[1] += q * k0.y; s[2] += q * k0.z; s[3] += q * k0.w;
                s[4] += q * k1.x; s[5] += q * k1.y; s[6] += q * k1.z; s[7] += q * k1.w;
            }
        }
        float tmax = -INFINITY;
        #pragma unroll
        for (int j = 0; j < 8; ++j) {
            float mf = (float)maskp[b * LL + m0 + mg * 8 + j];
            s[j] += -1e30f * (1.0f - mf);
            tmax = fmaxf(tmax, s[j]);
        }
        tmax = fmaxf(tmax, __shfl_xor(tmax, 1));
        tmax = fmaxf(tmax, __shfl_xor(tmax, 2));
        float nm = fmaxf(m_run, tmax);
        float corr = __expf(m_run - nm);
        float ws = 0.f;
        #pragma unroll
        for (int j = 0; j < 8; ++j) { s[j] = __expf(s[j] - nm); ws += s[j]; }
        ws += __shfl_xor(ws, 1);
        ws += __shfl_xor(ws, 2);
        l_run = l_run * corr + ws;
        m_run = nm;
        *(float4*)(Pl + r * 36 + mg * 8)     = make_float4(s[0], s[1], s[2], s[3]);
        *(float4*)(Pl + r * 36 + mg * 8 + 4) = make_float4(s[4], s[5], s[6], s[7]);
        __syncthreads();

        // ---- phase 2: oacc[16] for (row r, d = mg*16..+15)
        #pragma unroll
        for (int i = 0; i < 16; ++i) oacc[i] *= corr;
        #pragma unroll 2
        for (int m4 = 0; m4 < 8; ++m4) {
            float4 p4 = *(const float4*)(Pl + r * 36 + m4 * 4);
            #pragma unroll
            for (int mi = 0; mi < 4; ++mi) {
                float pv = (&p4.x)[mi];
                const float4* vp = (const float4*)(Vs + (m4 * 4 + mi) * 68 + mg * 16);
                float4 v0 = vp[0], v1 = vp[1], v2 = vp[2], v3 = vp[3];
                oacc[0]  += pv * v0.x; oacc[1]  += pv * v0.y; oacc[2]  += pv * v0.z; oacc[3]  += pv * v0.w;
                oacc[4]  += pv * v1.x; oacc[5]  += pv * v1.y; oacc[6]  += pv * v1.z; oacc[7]  += pv * v1.w;
                oacc[8]  += pv * v2.x; oacc[9]  += pv * v2.y; oacc[10] += pv * v2.z; oacc[11] += pv * v2.w;
                oacc[12] += pv * v3.x; oacc[13] += pv * v3.y; oacc[14] += pv * v3.z; oacc[15] += pv * v3.w;
            }
        }
    }

    float inv_l = 1.0f / l_run;
    #pragma unroll
    for (int dd = 0; dd < 16; ++dd) {
        int d = mg * 16 + dd;
        size_t idx = base + (size_t)d * LL + ql0 + r;
        outp[idx] = outp[idx] + oacc[dd] * inv_l;
    }
}

// ---------------------------------------------------------------- launch
extern "C" void kernel_launch(void* const* d_in, const int* in_sizes, int n_in,
                              void* d_out, int out_size, void* d_ws, size_t ws_size,
                              hipStream_t stream)
{
    const float* inputx  = (const float*)d_in[0];
    const int*   mask    = (const int*)  d_in[1];
    const float* ncs     = (const float*)d_in[4];
    const float* ncb     = (const float*)d_in[5];
    const float* dw_w    = (const float*)d_in[6];
    const float* pw_w    = (const float*)d_in[7];
    const float* pw_b    = (const float*)d_in[8];
    const float* ln1_s   = (const float*)d_in[9];
    const float* ln1_b   = (const float*)d_in[10];
    const float* ln2_s   = (const float*)d_in[11];
    const float* ln2_b   = (const float*)d_in[12];
    const float* w_kv    = (const float*)d_in[13];
    const float* w_q     = (const float*)d_in[14];
    const float* ffn1_w  = (const float*)d_in[15];
    const float* ffn1_b  = (const float*)d_in[16];
    const float* ffn2_w  = (const float*)d_in[17];
    const float* ffn2_b  = (const float*)d_in[18];

    float* ws = (float*)d_ws;
    const size_t NT = (size_t)BB * CC * LL;   // 8,388,608 floats
    float* result = ws;
    float* hbuf   = ws + NT;
    float* h2buf  = ws + 2 * NT;   // also q
    float* kbuf   = ws + 3 * NT;
    float* vbuf   = ws + 4 * NT;

    const int nelem = BB * CC * LL;
    dim3 blk(256);
    dim3 ggrid(LL / 128, CC / 128, BB);
    dim3 lgrid(LL / 64, BB);

    pos_enc_kernel<<<nelem / 256, blk, 0, stream>>>(inputx, result);

    for (int i = 0; i < NCONV; ++i) {
        ln_ch_kernel<<<lgrid, blk, 0, stream>>>(result, ncs + i * CC, ncb + i * CC, hbuf);
        dwconv_kernel<<<nelem / 256, blk, 0, stream>>>(hbuf, dw_w + i * CC * KW, h2buf);
        gemm_mfma_kernel<<<ggrid, blk, 0, stream>>>(pw_w + (size_t)i * CC * CC, h2buf, result,
                                                    pw_b + i * CC, result, CC, CC, 1, 1.0f);
    }

    // attention
    ln_ch_kernel<<<lgrid, blk, 0, stream>>>(result, ln1_s, ln1_b, hbuf);
    gemm_mfma_kernel<<<ggrid, blk, 0, stream>>>(w_kv,           hbuf, kbuf,  nullptr, nullptr, CC, CC, 0, 1.0f);
    gemm_mfma_kernel<<<ggrid, blk, 0, stream>>>(w_kv + CC * CC, hbuf, vbuf,  nullptr, nullptr, CC, CC, 0, 1.0f);
    gemm_mfma_kernel<<<ggrid, blk, 0, stream>>>(w_q,            hbuf, h2buf, nullptr, nullptr, CC, CC, 0, 0.125f);
    attn_kernel<<<dim3(LL / 64, NH, BB), blk, 0, stream>>>(h2buf, kbuf, vbuf, mask, result);

    // ffn
    ln_ch_kernel<<<lgrid, blk, 0, stream>>>(result, ln2_s, ln2_b, hbuf);
    gemm_mfma_kernel<<<ggrid, blk, 0, stream>>>(ffn1_w, hbuf, h2buf, ffn1_b, nullptr, CC, CC, 1, 1.0f);
    gemm_mfma_kernel<<<ggrid, blk, 0, stream>>>(ffn2_w, h2buf, (float*)d_out, ffn2_b, result, CC, CC, 0, 1.0f);
}

// Round 5
// 842.660 us; speedup vs baseline: 3.3096x; 1.6756x over previous
//
#include <hip/hip_runtime.h>
#include <math.h>

#define BB 16
#define CC 512
#define LL 1024
#define NCONV 4
#define KW 7
#define NH 8
#define DH 64

typedef short short8 __attribute__((ext_vector_type(8)));
typedef float f32x4  __attribute__((ext_vector_type(4)));

// ---------------------------------------------------------------- pos enc
__global__ __launch_bounds__(256) void pos_enc_kernel(
    const float* __restrict__ x, float* __restrict__ out)
{
    int idx = blockIdx.x * 256 + threadIdx.x;          // B*C*L total
    int l = idx & (LL - 1);
    int c = (idx >> 10) & (CC - 1);
    const float log_inc = 0.03611898185f;              // log(10000)/255
    int cc = (c < CC / 2) ? c : c - CC / 2;
    float inv = expf(-log_inc * (float)cc);
    float ph = (float)l * inv;
    float sig = (c < CC / 2) ? sinf(ph) : cosf(ph);
    out[idx] = x[idx] + sig;
}

// ---------------------------------------------------------------- layernorm over channels (fused stats+apply)
__global__ __launch_bounds__(256) void ln_ch_kernel(
    const float* __restrict__ x, const float* __restrict__ gam,
    const float* __restrict__ bet, float* __restrict__ out)
{
    int b = blockIdx.y;
    int l0 = blockIdx.x * 64;
    int lx = threadIdx.x & 63;
    int cg = threadIdx.x >> 6;        // 0..3
    const float* xb = x + (size_t)b * CC * LL + l0 + lx;

    float sum = 0.f, sumsq = 0.f;
    for (int c = cg * 128; c < cg * 128 + 128; ++c) {
        float v = xb[(size_t)c * LL];
        sum += v; sumsq += v * v;
    }
    __shared__ float s_sum[4][64], s_sq[4][64];
    __shared__ float s_mean[64], s_rstd[64];
    s_sum[cg][lx] = sum; s_sq[cg][lx] = sumsq;
    __syncthreads();
    if (cg == 0) {
        float tot  = s_sum[0][lx] + s_sum[1][lx] + s_sum[2][lx] + s_sum[3][lx];
        float tot2 = s_sq[0][lx]  + s_sq[1][lx]  + s_sq[2][lx]  + s_sq[3][lx];
        float mean = tot * (1.0f / CC);
        float var  = tot2 * (1.0f / CC) - mean * mean;
        s_mean[lx] = mean;
        s_rstd[lx] = rsqrtf(var + 1e-5f);
    }
    __syncthreads();
    float mean = s_mean[lx], rstd = s_rstd[lx];
    float* ob = out + (size_t)b * CC * LL + l0 + lx;
    for (int c = cg * 128; c < cg * 128 + 128; ++c) {
        float v = xb[(size_t)c * LL];
        ob[(size_t)c * LL] = (v - mean) * rstd * gam[c] + bet[c];
    }
}

// ---------------------------------------------------------------- depthwise conv K=7, pad 3
__global__ __launch_bounds__(256) void dwconv_kernel(
    const float* __restrict__ x, const float* __restrict__ w, float* __restrict__ out)
{
    int idx = blockIdx.x * 256 + threadIdx.x;
    int l = idx & (LL - 1);
    int bc = idx >> 10;
    int c = bc & (CC - 1);
    const float* wr = w + c * KW;
    const float* xr = x + (size_t)bc * LL;
    float acc = 0.f;
    #pragma unroll
    for (int k = 0; k < KW; ++k) {
        int ll = l + k - 3;
        float v = (ll >= 0 && ll < LL) ? xr[ll] : 0.0f;
        acc += wr[k] * v;
    }
    out[idx] = acc;
}

// ---------------------------------------------------------------- bf16 MFMA GEMM (unchanged from r3)
__global__ __launch_bounds__(256) void gemm_mfma_kernel(
    const float* __restrict__ Wm, const float* __restrict__ X,
    float* __restrict__ Y, const float* __restrict__ bias,
    const float* __restrict__ res, const int M, const int Kc,
    const int relu, const float scale)
{
    const int b  = blockIdx.z;
    const int l0 = blockIdx.x * 128;
    const int o0 = blockIdx.y * 128;
    const float* Xb = X + (size_t)b * Kc * LL;

    __shared__ __bf16 Wl[128 * 40];
    __shared__ __bf16 Xl[128 * 40];

    const int tid  = threadIdx.x;
    const int wave = tid >> 6;
    const int lane = tid & 63;
    const int wm = wave >> 1, wn = wave & 1;
    const int ln = lane & 15, kq = lane >> 4;

    f32x4 acc[4][4] = {};

    const int sm    = tid >> 1;
    const int shalf = tid & 1;
    const int sn    = tid & 127;
    const int skg   = tid >> 7;

    for (int k0 = 0; k0 < Kc; k0 += 32) {
        __syncthreads();
        {
            const float* src = Wm + (size_t)(o0 + sm) * Kc + k0 + shalf * 16;
            float4 f0 = *(const float4*)(src + 0);
            float4 f1 = *(const float4*)(src + 4);
            float4 f2 = *(const float4*)(src + 8);
            float4 f3 = *(const float4*)(src + 12);
            union { __bf16 h[16]; short8 s[2]; } u;
            u.h[0]=(__bf16)f0.x;  u.h[1]=(__bf16)f0.y;  u.h[2]=(__bf16)f0.z;  u.h[3]=(__bf16)f0.w;
            u.h[4]=(__bf16)f1.x;  u.h[5]=(__bf16)f1.y;  u.h[6]=(__bf16)f1.z;  u.h[7]=(__bf16)f1.w;
            u.h[8]=(__bf16)f2.x;  u.h[9]=(__bf16)f2.y;  u.h[10]=(__bf16)f2.z; u.h[11]=(__bf16)f2.w;
            u.h[12]=(__bf16)f3.x; u.h[13]=(__bf16)f3.y; u.h[14]=(__bf16)f3.z; u.h[15]=(__bf16)f3.w;
            short8* dst = (short8*)(Wl + sm * 40 + shalf * 16);
            dst[0] = u.s[0];
            dst[1] = u.s[1];
        }
        {
            #pragma unroll
            for (int j = 0; j < 8; ++j) {
                int kp = skg * 8 + j;
                float e0 = Xb[(size_t)(k0 + 2 * kp    ) * LL + l0 + sn];
                float e1 = Xb[(size_t)(k0 + 2 * kp + 1) * LL + l0 + sn];
                union { __bf16 h[2]; unsigned u; } pk;
                pk.h[0] = (__bf16)e0; pk.h[1] = (__bf16)e1;
                *(unsigned*)(Xl + sn * 40 + 2 * kp) = pk.u;
            }
        }
        __syncthreads();
        short8 af[4], bfr[4];
        #pragma unroll
        for (int mi = 0; mi < 4; ++mi)
            af[mi] = *(const short8*)(Wl + (wm * 64 + mi * 16 + ln) * 40 + kq * 8);
        #pragma unroll
        for (int ni = 0; ni < 4; ++ni)
            bfr[ni] = *(const short8*)(Xl + (wn * 64 + ni * 16 + ln) * 40 + kq * 8);
        #pragma unroll
        for (int mi = 0; mi < 4; ++mi)
            #pragma unroll
            for (int ni = 0; ni < 4; ++ni)
                acc[mi][ni] = __builtin_amdgcn_mfma_f32_16x16x32_bf16(
                    af[mi], bfr[ni], acc[mi][ni], 0, 0, 0);
    }

    const size_t ybase = (size_t)b * M * LL;
    #pragma unroll
    for (int mi = 0; mi < 4; ++mi) {
        const int mbase = o0 + wm * 64 + mi * 16 + kq * 4;
        #pragma unroll
        for (int ni = 0; ni < 4; ++ni) {
            const int n = l0 + wn * 64 + ni * 16 + ln;
            #pragma unroll
            for (int i = 0; i < 4; ++i) {
                const int m = mbase + i;
                float v = acc[mi][ni][i] * scale;
                if (bias) v += bias[m];
                if (relu) v = fmaxf(v, 0.f);
                size_t idx = ybase + (size_t)m * LL + n;
                if (res) v += res[idx];
                Y[idx] = v;
            }
        }
    }
}

// ---------------------------------------------------------------- MFMA flash attention (bf16 QK/PV, fp32 softmax)
// grid (L/64, H, B), 256 thr = 4 waves; wave w owns q-rows w*16..+15.
// D=64 => Q/K tiles need row stride >= 64: stride 72 (r4 bug was stride 40).
__global__ __launch_bounds__(256) void attn_mfma_kernel(
    const float* __restrict__ qb, const float* __restrict__ kb,
    const float* __restrict__ vb, const int* __restrict__ maskp,
    float* __restrict__ outp)
{
    const int b   = blockIdx.z;
    const int hh  = blockIdx.y;
    const int ql0 = blockIdx.x * 64;
    const int tid = threadIdx.x;
    const int w   = tid >> 6;
    const int lane = tid & 63;
    const int ln  = lane & 15;
    const int kq  = lane >> 4;

    __shared__ __bf16 Ql[64 * 72];   // [q][d]  stride 72 (64 payload + 8 pad)
    __shared__ __bf16 Kl[64 * 72];   // [m][d]
    __shared__ __bf16 Vl[64 * 72];   // [d][m]
    __shared__ __bf16 Pl[64 * 72];   // [q][m]

    const size_t base = (size_t)(b * CC + hh * DH) * LL;

    {   // stage Q transposed (once): pair-pack along d
        int qq = tid & 63, dg = tid >> 6;
        #pragma unroll
        for (int p = 0; p < 8; ++p) {
            int dp = dg * 8 + p;                       // d-pair 0..31
            float e0 = qb[base + (size_t)(2 * dp    ) * LL + ql0 + qq];
            float e1 = qb[base + (size_t)(2 * dp + 1) * LL + ql0 + qq];
            union { __bf16 h[2]; unsigned u; } pk;
            pk.h[0] = (__bf16)e0; pk.h[1] = (__bf16)e1;
            *(unsigned*)(Ql + qq * 72 + 2 * dp) = pk.u;
        }
    }

    float m_run[4], l_run[4];
    #pragma unroll
    for (int i = 0; i < 4; ++i) { m_run[i] = -INFINITY; l_run[i] = 0.f; }
    f32x4 oacc[4] = {};   // [d-subtile ni][reg i]; row q = w*16+kq*4+i, col d = ni*16+ln

    for (int m0 = 0; m0 < LL; m0 += 64) {
        __syncthreads();   // prev PV done; Q staged (iter 0)
        {   // stage K transposed: Kl[m][d], pair-packed b32 writes
            int mm = tid & 63, dg = tid >> 6;
            #pragma unroll
            for (int p = 0; p < 8; ++p) {
                int dp = dg * 8 + p;
                float e0 = kb[base + (size_t)(2 * dp    ) * LL + m0 + mm];
                float e1 = kb[base + (size_t)(2 * dp + 1) * LL + m0 + mm];
                union { __bf16 h[2]; unsigned u; } pk;
                pk.h[0] = (__bf16)e0; pk.h[1] = (__bf16)e1;
                *(unsigned*)(Kl + mm * 72 + 2 * dp) = pk.u;
            }
        }
        {   // stage V natural: Vl[d][m], float4 global -> 4xbf16 8B writes
            int mq = tid & 15, dr = tid >> 4;          // dr 0..15
            #pragma unroll
            for (int p = 0; p < 4; ++p) {
                int d = p * 16 + dr;
                float4 v4 = *(const float4*)(vb + base + (size_t)d * LL + m0 + mq * 4);
                union { __bf16 h[4]; unsigned u[2]; } pk;
                pk.h[0] = (__bf16)v4.x; pk.h[1] = (__bf16)v4.y;
                pk.h[2] = (__bf16)v4.z; pk.h[3] = (__bf16)v4.w;
                *(uint2*)(Vl + d * 72 + mq * 4) = make_uint2(pk.u[0], pk.u[1]);
            }
        }
        __syncthreads();

        // ---- QK^T: S[16 q][64 m] per wave
        f32x4 s[4] = {};
        {
            short8 aq[2];
            #pragma unroll
            for (int c = 0; c < 2; ++c)
                aq[c] = *(const short8*)(Ql + (w * 16 + ln) * 72 + c * 32 + kq * 8);
            #pragma unroll
            for (int ni = 0; ni < 4; ++ni) {
                #pragma unroll
                for (int c = 0; c < 2; ++c) {
                    short8 bk = *(const short8*)(Kl + (ni * 16 + ln) * 72 + c * 32 + kq * 8);
                    s[ni] = __builtin_amdgcn_mfma_f32_16x16x32_bf16(aq[c], bk, s[ni], 0, 0, 0);
                }
            }
        }

        // ---- online softmax; lane holds rows q=kq*4+i, cols m=m0+ni*16+ln
        float mf[4];
        #pragma unroll
        for (int ni = 0; ni < 4; ++ni)
            mf[ni] = (float)maskp[b * LL + m0 + ni * 16 + ln];
        float rmax[4];
        #pragma unroll
        for (int i = 0; i < 4; ++i) {
            float t = -INFINITY;
            #pragma unroll
            for (int ni = 0; ni < 4; ++ni) {
                s[ni][i] += -1e30f * (1.0f - mf[ni]);
                t = fmaxf(t, s[ni][i]);
            }
            rmax[i] = t;
        }
        #pragma unroll
        for (int off = 1; off < 16; off <<= 1)
            #pragma unroll
            for (int i = 0; i < 4; ++i)
                rmax[i] = fmaxf(rmax[i], __shfl_xor(rmax[i], off));

        float corr[4], rsum[4];
        #pragma unroll
        for (int i = 0; i < 4; ++i) {
            float nm = fmaxf(m_run[i], rmax[i]);
            corr[i] = __expf(m_run[i] - nm);
            m_run[i] = nm;
            float ssum = 0.f;
            #pragma unroll
            for (int ni = 0; ni < 4; ++ni) {
                float p = __expf(s[ni][i] - nm);
                s[ni][i] = p;
                ssum += p;
            }
            rsum[i] = ssum;
        }
        #pragma unroll
        for (int off = 1; off < 16; off <<= 1)
            #pragma unroll
            for (int i = 0; i < 4; ++i)
                rsum[i] += __shfl_xor(rsum[i], off);
        #pragma unroll
        for (int i = 0; i < 4; ++i)
            l_run[i] = l_run[i] * corr[i] + rsum[i];

        // rescale O, write P to LDS
        #pragma unroll
        for (int ni = 0; ni < 4; ++ni)
            #pragma unroll
            for (int i = 0; i < 4; ++i) {
                oacc[ni][i] *= corr[i];
                Pl[(w * 16 + kq * 4 + i) * 72 + ni * 16 + ln] = (__bf16)s[ni][i];
            }
        __syncthreads();

        // ---- PV: O[16 q][64 d] per wave; A=P[q][m], B=V[d][m]
        {
            short8 ap[2];
            #pragma unroll
            for (int c = 0; c < 2; ++c)
                ap[c] = *(const short8*)(Pl + (w * 16 + ln) * 72 + c * 32 + kq * 8);
            #pragma unroll
            for (int ni = 0; ni < 4; ++ni) {
                #pragma unroll
                for (int c = 0; c < 2; ++c) {
                    short8 bv = *(const short8*)(Vl + (ni * 16 + ln) * 72 + c * 32 + kq * 8);
                    oacc[ni] = __builtin_amdgcn_mfma_f32_16x16x32_bf16(ap[c], bv, oacc[ni], 0, 0, 0);
                }
            }
        }
    }

    // ---- epilogue: O /= l, residual add; reg i = consecutive l -> float4
    float inv_l[4];
    #pragma unroll
    for (int i = 0; i < 4; ++i) inv_l[i] = 1.0f / l_run[i];
    #pragma unroll
    for (int ni = 0; ni < 4; ++ni) {
        int d = ni * 16 + ln;
        size_t idx = base + (size_t)d * LL + ql0 + w * 16 + kq * 4;
        float4 r4 = *(const float4*)(outp + idx);
        r4.x += oacc[ni][0] * inv_l[0];
        r4.y += oacc[ni][1] * inv_l[1];
        r4.z += oacc[ni][2] * inv_l[2];
        r4.w += oacc[ni][3] * inv_l[3];
        *(float4*)(outp + idx) = r4;
    }
}

// ---------------------------------------------------------------- launch
extern "C" void kernel_launch(void* const* d_in, const int* in_sizes, int n_in,
                              void* d_out, int out_size, void* d_ws, size_t ws_size,
                              hipStream_t stream)
{
    const float* inputx  = (const float*)d_in[0];
    const int*   mask    = (const int*)  d_in[1];
    const float* ncs     = (const float*)d_in[4];
    const float* ncb     = (const float*)d_in[5];
    const float* dw_w    = (const float*)d_in[6];
    const float* pw_w    = (const float*)d_in[7];
    const float* pw_b    = (const float*)d_in[8];
    const float* ln1_s   = (const float*)d_in[9];
    const float* ln1_b   = (const float*)d_in[10];
    const float* ln2_s   = (const float*)d_in[11];
    const float* ln2_b   = (const float*)d_in[12];
    const float* w_kv    = (const float*)d_in[13];
    const float* w_q     = (const float*)d_in[14];
    const float* ffn1_w  = (const float*)d_in[15];
    const float* ffn1_b  = (const float*)d_in[16];
    const float* ffn2_w  = (const float*)d_in[17];
    const float* ffn2_b  = (const float*)d_in[18];

    float* ws = (float*)d_ws;
    const size_t NT = (size_t)BB * CC * LL;   // 8,388,608 floats
    float* result = ws;
    float* hbuf   = ws + NT;
    float* h2buf  = ws + 2 * NT;   // also q
    float* kbuf   = ws + 3 * NT;
    float* vbuf   = ws + 4 * NT;

    const int nelem = BB * CC * LL;
    dim3 blk(256);
    dim3 ggrid(LL / 128, CC / 128, BB);
    dim3 lgrid(LL / 64, BB);

    pos_enc_kernel<<<nelem / 256, blk, 0, stream>>>(inputx, result);

    for (int i = 0; i < NCONV; ++i) {
        ln_ch_kernel<<<lgrid, blk, 0, stream>>>(result, ncs + i * CC, ncb + i * CC, hbuf);
        dwconv_kernel<<<nelem / 256, blk, 0, stream>>>(hbuf, dw_w + i * CC * KW, h2buf);
        gemm_mfma_kernel<<<ggrid, blk, 0, stream>>>(pw_w + (size_t)i * CC * CC, h2buf, result,
                                                    pw_b + i * CC, result, CC, CC, 1, 1.0f);
    }

    // attention
    ln_ch_kernel<<<lgrid, blk, 0, stream>>>(result, ln1_s, ln1_b, hbuf);
    gemm_mfma_kernel<<<ggrid, blk, 0, stream>>>(w_kv,           hbuf, kbuf,  nullptr, nullptr, CC, CC, 0, 1.0f);
    gemm_mfma_kernel<<<ggrid, blk, 0, stream>>>(w_kv + CC * CC, hbuf, vbuf,  nullptr, nullptr, CC, CC, 0, 1.0f);
    gemm_mfma_kernel<<<ggrid, blk, 0, stream>>>(w_q,            hbuf, h2buf, nullptr, nullptr, CC, CC, 0, 0.125f);
    attn_mfma_kernel<<<dim3(LL / 64, NH, BB), blk, 0, stream>>>(h2buf, kbuf, vbuf, mask, result);

    // ffn
    ln_ch_kernel<<<lgrid, blk, 0, stream>>>(result, ln2_s, ln2_b, hbuf);
    gemm_mfma_kernel<<<ggrid, blk, 0, stream>>>(ffn1_w, hbuf, h2buf, ffn1_b, nullptr, CC, CC, 1, 1.0f);
    gemm_mfma_kernel<<<ggrid, blk, 0, stream>>>(ffn2_w, h2buf, (float*)d_out, ffn2_b, result, CC, CC, 0, 1.0f);
}

// Round 6
// 662.586 us; speedup vs baseline: 4.2090x; 1.2718x over previous
//
#include <hip/hip_runtime.h>
#include <math.h>

#define BB 16
#define CC 512
#define LL 1024
#define NCONV 4
#define KW 7
#define NH 8
#define DH 64

typedef short short8 __attribute__((ext_vector_type(8)));
typedef float f32x4  __attribute__((ext_vector_type(4)));

union bfpack2 { __bf16 h[2]; unsigned u; };
union bfpack4 { __bf16 h[4]; uint2 v; };
union bfpack8 { __bf16 h[8]; uint4 v; };

// ---------------------------------------------------------------- fp32 -> bf16 flat convert (weights)
__global__ __launch_bounds__(256) void f32_to_bf16_kernel(
    const float* __restrict__ in, __bf16* __restrict__ out, int n)
{
    int i = (blockIdx.x * 256 + threadIdx.x) * 4;
    if (i < n) {
        float4 f = *(const float4*)(in + i);
        bfpack4 p;
        p.h[0] = (__bf16)f.x; p.h[1] = (__bf16)f.y;
        p.h[2] = (__bf16)f.z; p.h[3] = (__bf16)f.w;
        *(uint2*)(out + i) = p.v;
    }
}

// ---------------------------------------------------------------- dw weights (NCONV,C,K) -> (NCONV,K,C) bf16
__global__ __launch_bounds__(256) void dw_transpose_kernel(
    const float* __restrict__ w, __bf16* __restrict__ wt)
{
    int t = blockIdx.x * 256 + threadIdx.x;
    if (t < NCONV * KW * CC) {
        int c = t & (CC - 1);
        int k = (t >> 9) % KW;
        int i = t / (KW * CC);
        wt[t] = (__bf16)w[(i * CC + c) * KW + k];
    }
}

// ---------------------------------------------------------------- pos enc + transpose (B,C,L) fp32 -> (B,L,C) fp32
__global__ __launch_bounds__(256) void pos_enc_t_kernel(
    const float* __restrict__ x, float* __restrict__ out)
{
    __shared__ float T[64 * 65];
    const int b = blockIdx.z, c0 = blockIdx.y * 64, l0 = blockIdx.x * 64;
    const int t = threadIdx.x;
    {
        int lt = t & 63, cr0 = t >> 6;
        #pragma unroll
        for (int j = 0; j < 16; ++j) {
            int cr = cr0 + 4 * j;
            T[cr * 65 + lt] = x[((size_t)b * CC + c0 + cr) * LL + l0 + lt];
        }
    }
    __syncthreads();
    {
        int ct = t & 63, lr0 = t >> 6;
        const float log_inc = 0.03611898185f;   // log(10000)/255
        int c = c0 + ct;
        int half = (c < CC / 2) ? c : c - CC / 2;
        float inv = expf(-log_inc * (float)half);
        #pragma unroll
        for (int j = 0; j < 16; ++j) {
            int lr = lr0 + 4 * j;
            int l = l0 + lr;
            float ph = (float)l * inv;
            float sig = (c < CC / 2) ? sinf(ph) : cosf(ph);
            out[((size_t)b * LL + l) * CC + c] = T[ct * 65 + lr] + sig;
        }
    }
}

// ---------------------------------------------------------------- layernorm over contiguous C, out bf16 (B,L,C)
// one wave per row; grid = B*L/4, block 256
__global__ __launch_bounds__(256) void ln_last_kernel(
    const float* __restrict__ x, const float* __restrict__ gam,
    const float* __restrict__ bet, __bf16* __restrict__ out)
{
    int row = blockIdx.x * 4 + (threadIdx.x >> 6);
    int ln = threadIdx.x & 63;
    const float* xr = x + (size_t)row * CC + ln * 8;
    float4 a = *(const float4*)xr;
    float4 c = *(const float4*)(xr + 4);
    float sum = a.x + a.y + a.z + a.w + c.x + c.y + c.z + c.w;
    float sq  = a.x*a.x + a.y*a.y + a.z*a.z + a.w*a.w
              + c.x*c.x + c.y*c.y + c.z*c.z + c.w*c.w;
    #pragma unroll
    for (int off = 1; off < 64; off <<= 1) {
        sum += __shfl_xor(sum, off);
        sq  += __shfl_xor(sq, off);
    }
    float mean = sum * (1.0f / CC);
    float rstd = rsqrtf(sq * (1.0f / CC) - mean * mean + 1e-5f);
    float4 g0 = *(const float4*)(gam + ln * 8);
    float4 g1 = *(const float4*)(gam + ln * 8 + 4);
    float4 b0 = *(const float4*)(bet + ln * 8);
    float4 b1 = *(const float4*)(bet + ln * 8 + 4);
    bfpack8 p;
    p.h[0] = (__bf16)((a.x - mean) * rstd * g0.x + b0.x);
    p.h[1] = (__bf16)((a.y - mean) * rstd * g0.y + b0.y);
    p.h[2] = (__bf16)((a.z - mean) * rstd * g0.z + b0.z);
    p.h[3] = (__bf16)((a.w - mean) * rstd * g0.w + b0.w);
    p.h[4] = (__bf16)((c.x - mean) * rstd * g1.x + b1.x);
    p.h[5] = (__bf16)((c.y - mean) * rstd * g1.y + b1.y);
    p.h[6] = (__bf16)((c.z - mean) * rstd * g1.z + b1.z);
    p.h[7] = (__bf16)((c.w - mean) * rstd * g1.w + b1.w);
    *(uint4*)(out + (size_t)row * CC + ln * 8) = p.v;
}

// ---------------------------------------------------------------- depthwise conv channel-last, bf16 in/out
// grid = B*L*64/256; thread: 8 contiguous c at one l
__global__ __launch_bounds__(256) void dwconv_last_kernel(
    const __bf16* __restrict__ x, const __bf16* __restrict__ wt,
    __bf16* __restrict__ out)
{
    int t = blockIdx.x * 256 + threadIdx.x;
    int c0 = (t & 63) * 8;
    int bl = t >> 6;
    int l = bl & (LL - 1);
    float acc[8] = {};
    #pragma unroll
    for (int k = 0; k < KW; ++k) {
        int ll = l + k - 3;
        if (ll < 0 || ll >= LL) continue;
        bfpack8 xv, wv;
        xv.v = *(const uint4*)(x + ((size_t)bl + (k - 3)) * CC + c0);
        wv.v = *(const uint4*)(wt + k * CC + c0);
        #pragma unroll
        for (int j = 0; j < 8; ++j)
            acc[j] += (float)xv.h[j] * (float)wv.h[j];
    }
    bfpack8 o;
    #pragma unroll
    for (int j = 0; j < 8; ++j) o.h[j] = (__bf16)acc[j];
    *(uint4*)(out + (size_t)bl * CC + c0) = o.v;
}

// ---------------------------------------------------------------- bf16 MFMA GEMM, all-bf16 staging, K=C=512
// W bf16 (M=512, K=512) row-major; X bf16 (B, L, C) rows l, k contiguous.
// mode 0: Y fp32 (B,L,C) RMW += relu(acc + bias)           (pw convs)
// mode 1: Y bf16 (B,L,C)  = opt-relu(acc*scale + opt bias) (q/kv/ffn1)
// mode 2: swapped operands; Y fp32 (B,C,L) = acc + bias + res(B,L,C)  (ffn2)
__global__ __launch_bounds__(256) void gemm_bf_kernel(
    const __bf16* __restrict__ Wm, const __bf16* __restrict__ X,
    void* __restrict__ Yv, const float* __restrict__ bias,
    const float* __restrict__ res, const int mode, const int relu,
    const float scale)
{
    const int b  = blockIdx.z;
    const int l0 = blockIdx.x * 128;
    const int o0 = blockIdx.y * 128;
    const __bf16* Xb = X + (size_t)b * LL * CC;

    __shared__ __bf16 Al[128 * 40];
    __shared__ __bf16 Bl[128 * 40];

    const int tid = threadIdx.x;
    const int wave = tid >> 6, lane = tid & 63;
    const int wm = wave >> 1, wn = wave & 1;
    const int ln = lane & 15, kq = lane >> 4;

    const __bf16* Aptr = (mode == 2) ? (Xb + (size_t)l0 * CC) : (Wm + (size_t)o0 * CC);
    const __bf16* Bptr = (mode == 2) ? (Wm + (size_t)o0 * CC) : (Xb + (size_t)l0 * CC);

    f32x4 acc[4][4] = {};

    const int r0 = tid >> 2;            // 0..63
    const int ce = (tid & 3) * 8;       // element offset within 32-k tile

    for (int k0 = 0; k0 < CC; k0 += 32) {
        uint4 a0 = *(const uint4*)(Aptr + (size_t)r0 * CC + k0 + ce);
        uint4 a1 = *(const uint4*)(Aptr + (size_t)(r0 + 64) * CC + k0 + ce);
        uint4 b0 = *(const uint4*)(Bptr + (size_t)r0 * CC + k0 + ce);
        uint4 b1 = *(const uint4*)(Bptr + (size_t)(r0 + 64) * CC + k0 + ce);
        __syncthreads();                 // prev iter frag reads done
        *(uint4*)(Al + r0 * 40 + ce)        = a0;
        *(uint4*)(Al + (r0 + 64) * 40 + ce) = a1;
        *(uint4*)(Bl + r0 * 40 + ce)        = b0;
        *(uint4*)(Bl + (r0 + 64) * 40 + ce) = b1;
        __syncthreads();
        short8 af[4], bf[4];
        #pragma unroll
        for (int mi = 0; mi < 4; ++mi)
            af[mi] = *(const short8*)(Al + (wm * 64 + mi * 16 + ln) * 40 + kq * 8);
        #pragma unroll
        for (int ni = 0; ni < 4; ++ni)
            bf[ni] = *(const short8*)(Bl + (wn * 64 + ni * 16 + ln) * 40 + kq * 8);
        #pragma unroll
        for (int mi = 0; mi < 4; ++mi)
            #pragma unroll
            for (int ni = 0; ni < 4; ++ni)
                acc[mi][ni] = __builtin_amdgcn_mfma_f32_16x16x32_bf16(
                    af[mi], bf[ni], acc[mi][ni], 0, 0, 0);
    }

    if (mode == 0) {
        float* Y = (float*)Yv;           // (B,L,C), in-place residual
        #pragma unroll
        for (int mi = 0; mi < 4; ++mi) {
            int cb = o0 + wm * 64 + mi * 16 + kq * 4;
            #pragma unroll
            for (int ni = 0; ni < 4; ++ni) {
                int l = l0 + wn * 64 + ni * 16 + ln;
                size_t idx = ((size_t)b * LL + l) * CC + cb;
                float4 r4 = *(const float4*)(Y + idx);
                float4 v;
                v.x = fmaxf(acc[mi][ni][0] + bias[cb + 0], 0.f) + r4.x;
                v.y = fmaxf(acc[mi][ni][1] + bias[cb + 1], 0.f) + r4.y;
                v.z = fmaxf(acc[mi][ni][2] + bias[cb + 2], 0.f) + r4.z;
                v.w = fmaxf(acc[mi][ni][3] + bias[cb + 3], 0.f) + r4.w;
                *(float4*)(Y + idx) = v;
            }
        }
    } else if (mode == 1) {
        __bf16* Y = (__bf16*)Yv;         // (B,L,C)
        #pragma unroll
        for (int mi = 0; mi < 4; ++mi) {
            int cb = o0 + wm * 64 + mi * 16 + kq * 4;
            #pragma unroll
            for (int ni = 0; ni < 4; ++ni) {
                int l = l0 + wn * 64 + ni * 16 + ln;
                bfpack4 p;
                #pragma unroll
                for (int i = 0; i < 4; ++i) {
                    float v = acc[mi][ni][i] * scale;
                    if (bias) v += bias[cb + i];
                    if (relu) v = fmaxf(v, 0.f);
                    p.h[i] = (__bf16)v;
                }
                *(uint2*)(Y + ((size_t)b * LL + l) * CC + cb) = p.v;
            }
        }
    } else {
        float* Y = (float*)Yv;           // (B,C,L)
        #pragma unroll
        for (int mi = 0; mi < 4; ++mi) {
            int lb = l0 + wm * 64 + mi * 16 + kq * 4;
            #pragma unroll
            for (int ni = 0; ni < 4; ++ni) {
                int c = o0 + wn * 64 + ni * 16 + ln;
                float bv = bias[c];
                const float* rp = res + ((size_t)b * LL + lb) * CC + c;
                float4 v;
                v.x = acc[mi][ni][0] + bv + rp[0 * CC];
                v.y = acc[mi][ni][1] + bv + rp[1 * CC];
                v.z = acc[mi][ni][2] + bv + rp[2 * CC];
                v.w = acc[mi][ni][3] + bv + rp[3 * CC];
                *(float4*)(Y + ((size_t)b * CC + c) * LL + lb) = v;
            }
        }
    }
}

// ---------------------------------------------------------------- MFMA flash attention, bf16 channel-last QKV
// grid (L/64, H, B). Q/K/V bf16 (B,L,C); head = columns hh*64..+63.
// outp fp32 (B,L,C) residual RMW.
__global__ __launch_bounds__(256) void attn_mfma_kernel(
    const __bf16* __restrict__ qb, const __bf16* __restrict__ kb,
    const __bf16* __restrict__ vb, const int* __restrict__ maskp,
    float* __restrict__ outp)
{
    const int b = blockIdx.z, hh = blockIdx.y, ql0 = blockIdx.x * 64;
    const int tid = threadIdx.x, w = tid >> 6, lane = tid & 63;
    const int ln = lane & 15, kq = lane >> 4;

    __shared__ __bf16 Ql[64 * 72];   // [q][d]
    __shared__ __bf16 Kl[64 * 72];   // [m][d]
    __shared__ __bf16 Vl[64 * 72];   // [d][m]  (transposed)
    __shared__ __bf16 Pl[64 * 72];   // [q][m]
    __shared__ float corrS[64], invS[64];

    const int co = hh * 64;

    {   // stage Q (no transpose: rows already k-contiguous)
        #pragma unroll
        for (int j = 0; j < 2; ++j) {
            int q = tid + 256 * j;
            int r = q >> 3, c8 = (q & 7) * 8;
            uint4 v = *(const uint4*)(qb + ((size_t)b * LL + ql0 + r) * CC + co + c8);
            *(uint4*)(Ql + r * 72 + c8) = v;
        }
    }

    float m_run[4], l_run[4];
    #pragma unroll
    for (int i = 0; i < 4; ++i) { m_run[i] = -INFINITY; l_run[i] = 0.f; }
    f32x4 oacc[4] = {};   // PV D-space: d = ni*16+kq*4+i, q = w*16+ln

    for (int m0 = 0; m0 < LL; m0 += 64) {
        __syncthreads();
        {   // stage K rows m
            #pragma unroll
            for (int j = 0; j < 2; ++j) {
                int q = tid + 256 * j;
                int r = q >> 3, c8 = (q & 7) * 8;
                uint4 v = *(const uint4*)(kb + ((size_t)b * LL + m0 + r) * CC + co + c8);
                *(uint4*)(Kl + r * 72 + c8) = v;
            }
        }
        {   // stage V transposed: Vl[d][m] pair-packed (conflict-free b32 writes)
            int mp = tid & 31, dg = tid >> 5;
            #pragma unroll
            for (int p = 0; p < 8; ++p) {
                int d = dg * 8 + p;
                const __bf16* vp = vb + ((size_t)b * LL + m0 + 2 * mp) * CC + co + d;
                bfpack2 pk;
                pk.h[0] = vp[0];
                pk.h[1] = vp[CC];
                *(unsigned*)(Vl + d * 72 + 2 * mp) = pk.u;
            }
        }
        __syncthreads();

        // ---- QK^T: D[q][m]; lane rows q=kq*4+i, cols m=ni*16+ln
        f32x4 s[4] = {};
        {
            short8 aq[2];
            #pragma unroll
            for (int c = 0; c < 2; ++c)
                aq[c] = *(const short8*)(Ql + (w * 16 + ln) * 72 + c * 32 + kq * 8);
            #pragma unroll
            for (int ni = 0; ni < 4; ++ni)
                #pragma unroll
                for (int c = 0; c < 2; ++c) {
                    short8 bk = *(const short8*)(Kl + (ni * 16 + ln) * 72 + c * 32 + kq * 8);
                    s[ni] = __builtin_amdgcn_mfma_f32_16x16x32_bf16(aq[c], bk, s[ni], 0, 0, 0);
                }
        }

        // ---- online softmax
        float mf[4];
        #pragma unroll
        for (int ni = 0; ni < 4; ++ni)
            mf[ni] = (float)maskp[b * LL + m0 + ni * 16 + ln];
        float rmax[4];
        #pragma unroll
        for (int i = 0; i < 4; ++i) {
            float t = -INFINITY;
            #pragma unroll
            for (int ni = 0; ni < 4; ++ni) {
                s[ni][i] += -1e30f * (1.0f - mf[ni]);
                t = fmaxf(t, s[ni][i]);
            }
            rmax[i] = t;
        }
        #pragma unroll
        for (int off = 1; off < 16; off <<= 1)
            #pragma unroll
            for (int i = 0; i < 4; ++i)
                rmax[i] = fmaxf(rmax[i], __shfl_xor(rmax[i], off));

        float corr[4], rsum[4];
        #pragma unroll
        for (int i = 0; i < 4; ++i) {
            float nm = fmaxf(m_run[i], rmax[i]);
            corr[i] = __expf(m_run[i] - nm);
            m_run[i] = nm;
            float ssum = 0.f;
            #pragma unroll
            for (int ni = 0; ni < 4; ++ni) {
                float p = __expf(s[ni][i] - nm);
                s[ni][i] = p;
                ssum += p;
            }
            rsum[i] = ssum;
        }
        #pragma unroll
        for (int off = 1; off < 16; off <<= 1)
            #pragma unroll
            for (int i = 0; i < 4; ++i)
                rsum[i] += __shfl_xor(rsum[i], off);
        #pragma unroll
        for (int i = 0; i < 4; ++i)
            l_run[i] = l_run[i] * corr[i] + rsum[i];

        if (ln == 0) {
            #pragma unroll
            for (int i = 0; i < 4; ++i) corrS[w * 16 + kq * 4 + i] = corr[i];
        }
        #pragma unroll
        for (int ni = 0; ni < 4; ++ni)
            #pragma unroll
            for (int i = 0; i < 4; ++i)
                Pl[(w * 16 + kq * 4 + i) * 72 + ni * 16 + ln] = (__bf16)s[ni][i];
        __syncthreads();

        // ---- PV: D[d][q]; A = V^T rows d, B = P rows q
        float oc = corrS[w * 16 + ln];
        short8 bp[2];
        #pragma unroll
        for (int c = 0; c < 2; ++c)
            bp[c] = *(const short8*)(Pl + (w * 16 + ln) * 72 + c * 32 + kq * 8);
        #pragma unroll
        for (int ni = 0; ni < 4; ++ni) {
            #pragma unroll
            for (int i = 0; i < 4; ++i) oacc[ni][i] *= oc;
            #pragma unroll
            for (int c = 0; c < 2; ++c) {
                short8 av = *(const short8*)(Vl + (ni * 16 + ln) * 72 + c * 32 + kq * 8);
                oacc[ni] = __builtin_amdgcn_mfma_f32_16x16x32_bf16(av, bp[c], oacc[ni], 0, 0, 0);
            }
        }
    }

    if (ln == 0) {
        #pragma unroll
        for (int i = 0; i < 4; ++i) invS[w * 16 + kq * 4 + i] = 1.0f / l_run[i];
    }
    __syncthreads();
    float inv = invS[w * 16 + ln];
    int l = ql0 + w * 16 + ln;
    #pragma unroll
    for (int ni = 0; ni < 4; ++ni) {
        int c = co + ni * 16 + kq * 4;
        size_t idx = ((size_t)b * LL + l) * CC + c;
        float4 r4 = *(const float4*)(outp + idx);
        r4.x += oacc[ni][0] * inv;
        r4.y += oacc[ni][1] * inv;
        r4.z += oacc[ni][2] * inv;
        r4.w += oacc[ni][3] * inv;
        *(float4*)(outp + idx) = r4;
    }
}

// ---------------------------------------------------------------- launch
extern "C" void kernel_launch(void* const* d_in, const int* in_sizes, int n_in,
                              void* d_out, int out_size, void* d_ws, size_t ws_size,
                              hipStream_t stream)
{
    const float* inputx  = (const float*)d_in[0];
    const int*   mask    = (const int*)  d_in[1];
    const float* ncs     = (const float*)d_in[4];
    const float* ncb     = (const float*)d_in[5];
    const float* dw_w    = (const float*)d_in[6];
    const float* pw_w    = (const float*)d_in[7];
    const float* pw_b    = (const float*)d_in[8];
    const float* ln1_s   = (const float*)d_in[9];
    const float* ln1_b   = (const float*)d_in[10];
    const float* ln2_s   = (const float*)d_in[11];
    const float* ln2_b   = (const float*)d_in[12];
    const float* w_kv    = (const float*)d_in[13];
    const float* w_q     = (const float*)d_in[14];
    const float* ffn1_w  = (const float*)d_in[15];
    const float* ffn1_b  = (const float*)d_in[16];
    const float* ffn2_w  = (const float*)d_in[17];
    const float* ffn2_b  = (const float*)d_in[18];

    const size_t NT = (size_t)BB * CC * LL;
    float*  result = (float*)d_ws;                 // fp32 (B,L,C)
    __bf16* wsb  = (__bf16*)(result + NT);
    __bf16* hb   = wsb;                            // ln output  (B,L,C)
    __bf16* xb   = wsb + NT;                       // dwconv out / ffn hidden
    __bf16* qbuf = wsb + 2 * NT;
    __bf16* kbuf = wsb + 3 * NT;
    __bf16* vbuf = wsb + 4 * NT;
    __bf16* wpw  = wsb + 5 * NT;                   // 4*C*C
    __bf16* wkv  = wpw + 4 * CC * CC;              // 2*C*C
    __bf16* wq   = wkv + 2 * CC * CC;
    __bf16* wf1  = wq + CC * CC;
    __bf16* wf2  = wf1 + CC * CC;
    __bf16* dwt  = wf2 + CC * CC;                  // 4*K*C

    dim3 blk(256);
    dim3 ggrid(LL / 128, CC / 128, BB);

    // weight prep
    f32_to_bf16_kernel<<<(4 * CC * CC) / 1024, blk, 0, stream>>>(pw_w, wpw, 4 * CC * CC);
    f32_to_bf16_kernel<<<(2 * CC * CC) / 1024, blk, 0, stream>>>(w_kv, wkv, 2 * CC * CC);
    f32_to_bf16_kernel<<<(CC * CC) / 1024, blk, 0, stream>>>(w_q, wq, CC * CC);
    f32_to_bf16_kernel<<<(CC * CC) / 1024, blk, 0, stream>>>(ffn1_w, wf1, CC * CC);
    f32_to_bf16_kernel<<<(CC * CC) / 1024, blk, 0, stream>>>(ffn2_w, wf2, CC * CC);
    dw_transpose_kernel<<<(NCONV * KW * CC + 255) / 256, blk, 0, stream>>>(dw_w, dwt);

    pos_enc_t_kernel<<<dim3(LL / 64, CC / 64, BB), blk, 0, stream>>>(inputx, result);

    for (int i = 0; i < NCONV; ++i) {
        ln_last_kernel<<<BB * LL / 4, blk, 0, stream>>>(result, ncs + i * CC, ncb + i * CC, hb);
        dwconv_last_kernel<<<BB * LL * 64 / 256, blk, 0, stream>>>(hb, dwt + i * KW * CC, xb);
        gemm_bf_kernel<<<ggrid, blk, 0, stream>>>(wpw + (size_t)i * CC * CC, xb, result,
                                                  pw_b + i * CC, nullptr, 0, 1, 1.0f);
    }

    // attention
    ln_last_kernel<<<BB * LL / 4, blk, 0, stream>>>(result, ln1_s, ln1_b, hb);
    gemm_bf_kernel<<<ggrid, blk, 0, stream>>>(wkv,           hb, kbuf, nullptr, nullptr, 1, 0, 1.0f);
    gemm_bf_kernel<<<ggrid, blk, 0, stream>>>(wkv + CC * CC, hb, vbuf, nullptr, nullptr, 1, 0, 1.0f);
    gemm_bf_kernel<<<ggrid, blk, 0, stream>>>(wq,            hb, qbuf, nullptr, nullptr, 1, 0, 0.125f);
    attn_mfma_kernel<<<dim3(LL / 64, NH, BB), blk, 0, stream>>>(qbuf, kbuf, vbuf, mask, result);

    // ffn
    ln_last_kernel<<<BB * LL / 4, blk, 0, stream>>>(result, ln2_s, ln2_b, hb);
    gemm_bf_kernel<<<ggrid, blk, 0, stream>>>(wf1, hb, xb, ffn1_b, nullptr, 1, 1, 1.0f);
    gemm_bf_kernel<<<ggrid, blk, 0, stream>>>(wf2, xb, d_out, ffn2_b, result, 2, 0, 1.0f);
}

// Round 7
// 630.994 us; speedup vs baseline: 4.4198x; 1.0501x over previous
//
#include <hip/hip_runtime.h>
#include <math.h>

#define BB 16
#define CC 512
#define LL 1024
#define NCONV 4
#define KW 7
#define NH 8
#define DH 64

typedef short short8 __attribute__((ext_vector_type(8)));
typedef float f32x4  __attribute__((ext_vector_type(4)));

union bfpack2 { __bf16 h[2]; unsigned u; };
union bfpack4 { __bf16 h[4]; uint2 v; };
union bfpack8 { __bf16 h[8]; uint4 v; };

// ---------------------------------------------------------------- fp32 -> bf16 flat convert (weights)
__global__ __launch_bounds__(256) void f32_to_bf16_kernel(
    const float* __restrict__ in, __bf16* __restrict__ out, int n)
{
    int i = (blockIdx.x * 256 + threadIdx.x) * 4;
    if (i < n) {
        float4 f = *(const float4*)(in + i);
        bfpack4 p;
        p.h[0] = (__bf16)f.x; p.h[1] = (__bf16)f.y;
        p.h[2] = (__bf16)f.z; p.h[3] = (__bf16)f.w;
        *(uint2*)(out + i) = p.v;
    }
}

// ---------------------------------------------------------------- dw weights (NCONV,C,K) -> (NCONV,K,C) bf16
__global__ __launch_bounds__(256) void dw_transpose_kernel(
    const float* __restrict__ w, __bf16* __restrict__ wt)
{
    int t = blockIdx.x * 256 + threadIdx.x;
    if (t < NCONV * KW * CC) {
        int c = t & (CC - 1);
        int k = (t >> 9) % KW;
        int i = t / (KW * CC);
        wt[t] = (__bf16)w[(i * CC + c) * KW + k];
    }
}

// ---------------------------------------------------------------- pos enc + transpose (B,C,L) fp32 -> (B,L,C) fp32
__global__ __launch_bounds__(256) void pos_enc_t_kernel(
    const float* __restrict__ x, float* __restrict__ out)
{
    __shared__ float T[64 * 65];
    const int b = blockIdx.z, c0 = blockIdx.y * 64, l0 = blockIdx.x * 64;
    const int t = threadIdx.x;
    {
        int lt = t & 63, cr0 = t >> 6;
        #pragma unroll
        for (int j = 0; j < 16; ++j) {
            int cr = cr0 + 4 * j;
            T[cr * 65 + lt] = x[((size_t)b * CC + c0 + cr) * LL + l0 + lt];
        }
    }
    __syncthreads();
    {
        int ct = t & 63, lr0 = t >> 6;
        const float log_inc = 0.03611898185f;   // log(10000)/255
        int c = c0 + ct;
        int half = (c < CC / 2) ? c : c - CC / 2;
        float inv = expf(-log_inc * (float)half);
        #pragma unroll
        for (int j = 0; j < 16; ++j) {
            int lr = lr0 + 4 * j;
            int l = l0 + lr;
            float ph = (float)l * inv;
            float sig = (c < CC / 2) ? sinf(ph) : cosf(ph);
            out[((size_t)b * LL + l) * CC + c] = T[ct * 65 + lr] + sig;
        }
    }
}

// ---------------------------------------------------------------- layernorm over contiguous C, out bf16 (B,L,C)
__global__ __launch_bounds__(256) void ln_last_kernel(
    const float* __restrict__ x, const float* __restrict__ gam,
    const float* __restrict__ bet, __bf16* __restrict__ out)
{
    int row = blockIdx.x * 4 + (threadIdx.x >> 6);
    int ln = threadIdx.x & 63;
    const float* xr = x + (size_t)row * CC + ln * 8;
    float4 a = *(const float4*)xr;
    float4 c = *(const float4*)(xr + 4);
    float sum = a.x + a.y + a.z + a.w + c.x + c.y + c.z + c.w;
    float sq  = a.x*a.x + a.y*a.y + a.z*a.z + a.w*a.w
              + c.x*c.x + c.y*c.y + c.z*c.z + c.w*c.w;
    #pragma unroll
    for (int off = 1; off < 64; off <<= 1) {
        sum += __shfl_xor(sum, off);
        sq  += __shfl_xor(sq, off);
    }
    float mean = sum * (1.0f / CC);
    float rstd = rsqrtf(sq * (1.0f / CC) - mean * mean + 1e-5f);
    float4 g0 = *(const float4*)(gam + ln * 8);
    float4 g1 = *(const float4*)(gam + ln * 8 + 4);
    float4 b0 = *(const float4*)(bet + ln * 8);
    float4 b1 = *(const float4*)(bet + ln * 8 + 4);
    bfpack8 p;
    p.h[0] = (__bf16)((a.x - mean) * rstd * g0.x + b0.x);
    p.h[1] = (__bf16)((a.y - mean) * rstd * g0.y + b0.y);
    p.h[2] = (__bf16)((a.z - mean) * rstd * g0.z + b0.z);
    p.h[3] = (__bf16)((a.w - mean) * rstd * g0.w + b0.w);
    p.h[4] = (__bf16)((c.x - mean) * rstd * g1.x + b1.x);
    p.h[5] = (__bf16)((c.y - mean) * rstd * g1.y + b1.y);
    p.h[6] = (__bf16)((c.z - mean) * rstd * g1.z + b1.z);
    p.h[7] = (__bf16)((c.w - mean) * rstd * g1.w + b1.w);
    *(uint4*)(out + (size_t)row * CC + ln * 8) = p.v;
}

// ---------------------------------------------------------------- depthwise conv channel-last, bf16 in/out
__global__ __launch_bounds__(256) void dwconv_last_kernel(
    const __bf16* __restrict__ x, const __bf16* __restrict__ wt,
    __bf16* __restrict__ out)
{
    int t = blockIdx.x * 256 + threadIdx.x;
    int c0 = (t & 63) * 8;
    int bl = t >> 6;
    int l = bl & (LL - 1);
    float acc[8] = {};
    #pragma unroll
    for (int k = 0; k < KW; ++k) {
        int ll = l + k - 3;
        if (ll < 0 || ll >= LL) continue;
        bfpack8 xv, wv;
        xv.v = *(const uint4*)(x + ((size_t)bl + (k - 3)) * CC + c0);
        wv.v = *(const uint4*)(wt + k * CC + c0);
        #pragma unroll
        for (int j = 0; j < 8; ++j)
            acc[j] += (float)xv.h[j] * (float)wv.h[j];
    }
    bfpack8 o;
    #pragma unroll
    for (int j = 0; j < 8; ++j) o.h[j] = (__bf16)acc[j];
    *(uint4*)(out + (size_t)bl * CC + c0) = o.v;
}

// ---------------------------------------------------------------- bf16 MFMA GEMM, register-prefetched K-loop
// W bf16 (M=512, K=512) row-major; X bf16 (B, L, C).
// mode 0: Y fp32 (B,L,C) RMW += relu(acc + bias)
// mode 1: Y bf16 (B,L,C)  = opt-relu(acc*scale + opt bias)
// mode 2: swapped; Y fp32 (B,C,L) = acc + bias + res(B,L,C)
// mode 3: swapped; Y bf16 (B,C,L) = acc
__global__ __launch_bounds__(256) void gemm_bf_kernel(
    const __bf16* __restrict__ Wm, const __bf16* __restrict__ X,
    void* __restrict__ Yv, const float* __restrict__ bias,
    const float* __restrict__ res, const int mode, const int relu,
    const float scale)
{
    const int b  = blockIdx.z;
    const int l0 = blockIdx.x * 128;
    const int o0 = blockIdx.y * 128;
    const __bf16* Xb = X + (size_t)b * LL * CC;

    __shared__ __bf16 Al[128 * 40];
    __shared__ __bf16 Bl[128 * 40];

    const int tid = threadIdx.x;
    const int wave = tid >> 6, lane = tid & 63;
    const int wm = wave >> 1, wn = wave & 1;
    const int ln = lane & 15, kq = lane >> 4;

    const int swapped = (mode >= 2);
    const __bf16* Aptr = swapped ? (Xb + (size_t)l0 * CC) : (Wm + (size_t)o0 * CC);
    const __bf16* Bptr = swapped ? (Wm + (size_t)o0 * CC) : (Xb + (size_t)l0 * CC);

    f32x4 acc[4][4] = {};

    const int r0 = tid >> 2;
    const int ce = (tid & 3) * 8;

    // prefetch iter 0
    uint4 a0 = *(const uint4*)(Aptr + (size_t)r0 * CC + ce);
    uint4 a1 = *(const uint4*)(Aptr + (size_t)(r0 + 64) * CC + ce);
    uint4 b0 = *(const uint4*)(Bptr + (size_t)r0 * CC + ce);
    uint4 b1 = *(const uint4*)(Bptr + (size_t)(r0 + 64) * CC + ce);

    for (int k0 = 0; k0 < CC; k0 += 32) {
        __syncthreads();                 // prev iter frag reads done
        *(uint4*)(Al + r0 * 40 + ce)        = a0;
        *(uint4*)(Al + (r0 + 64) * 40 + ce) = a1;
        *(uint4*)(Bl + r0 * 40 + ce)        = b0;
        *(uint4*)(Bl + (r0 + 64) * 40 + ce) = b1;
        __syncthreads();
        // issue next iter's loads; they overlap frag reads + MFMAs below
        int kn = (k0 + 32 < CC) ? k0 + 32 : k0;
        a0 = *(const uint4*)(Aptr + (size_t)r0 * CC + kn + ce);
        a1 = *(const uint4*)(Aptr + (size_t)(r0 + 64) * CC + kn + ce);
        b0 = *(const uint4*)(Bptr + (size_t)r0 * CC + kn + ce);
        b1 = *(const uint4*)(Bptr + (size_t)(r0 + 64) * CC + kn + ce);

        short8 af[4], bf[4];
        #pragma unroll
        for (int mi = 0; mi < 4; ++mi)
            af[mi] = *(const short8*)(Al + (wm * 64 + mi * 16 + ln) * 40 + kq * 8);
        #pragma unroll
        for (int ni = 0; ni < 4; ++ni)
            bf[ni] = *(const short8*)(Bl + (wn * 64 + ni * 16 + ln) * 40 + kq * 8);
        #pragma unroll
        for (int mi = 0; mi < 4; ++mi)
            #pragma unroll
            for (int ni = 0; ni < 4; ++ni)
                acc[mi][ni] = __builtin_amdgcn_mfma_f32_16x16x32_bf16(
                    af[mi], bf[ni], acc[mi][ni], 0, 0, 0);
    }

    if (mode == 0) {
        float* Y = (float*)Yv;           // (B,L,C), in-place residual
        #pragma unroll
        for (int mi = 0; mi < 4; ++mi) {
            int cb = o0 + wm * 64 + mi * 16 + kq * 4;
            #pragma unroll
            for (int ni = 0; ni < 4; ++ni) {
                int l = l0 + wn * 64 + ni * 16 + ln;
                size_t idx = ((size_t)b * LL + l) * CC + cb;
                float4 r4 = *(const float4*)(Y + idx);
                float4 v;
                v.x = fmaxf(acc[mi][ni][0] + bias[cb + 0], 0.f) + r4.x;
                v.y = fmaxf(acc[mi][ni][1] + bias[cb + 1], 0.f) + r4.y;
                v.z = fmaxf(acc[mi][ni][2] + bias[cb + 2], 0.f) + r4.z;
                v.w = fmaxf(acc[mi][ni][3] + bias[cb + 3], 0.f) + r4.w;
                *(float4*)(Y + idx) = v;
            }
        }
    } else if (mode == 1) {
        __bf16* Y = (__bf16*)Yv;         // (B,L,C)
        #pragma unroll
        for (int mi = 0; mi < 4; ++mi) {
            int cb = o0 + wm * 64 + mi * 16 + kq * 4;
            #pragma unroll
            for (int ni = 0; ni < 4; ++ni) {
                int l = l0 + wn * 64 + ni * 16 + ln;
                bfpack4 p;
                #pragma unroll
                for (int i = 0; i < 4; ++i) {
                    float v = acc[mi][ni][i] * scale;
                    if (bias) v += bias[cb + i];
                    if (relu) v = fmaxf(v, 0.f);
                    p.h[i] = (__bf16)v;
                }
                *(uint2*)(Y + ((size_t)b * LL + l) * CC + cb) = p.v;
            }
        }
    } else if (mode == 2) {
        float* Y = (float*)Yv;           // (B,C,L)
        #pragma unroll
        for (int mi = 0; mi < 4; ++mi) {
            int lb = l0 + wm * 64 + mi * 16 + kq * 4;
            #pragma unroll
            for (int ni = 0; ni < 4; ++ni) {
                int c = o0 + wn * 64 + ni * 16 + ln;
                float bv = bias[c];
                const float* rp = res + ((size_t)b * LL + lb) * CC + c;
                float4 v;
                v.x = acc[mi][ni][0] + bv + rp[0 * CC];
                v.y = acc[mi][ni][1] + bv + rp[1 * CC];
                v.z = acc[mi][ni][2] + bv + rp[2 * CC];
                v.w = acc[mi][ni][3] + bv + rp[3 * CC];
                *(float4*)(Y + ((size_t)b * CC + c) * LL + lb) = v;
            }
        }
    } else {
        __bf16* Y = (__bf16*)Yv;         // (B,C,L) bf16
        #pragma unroll
        for (int mi = 0; mi < 4; ++mi) {
            int lb = l0 + wm * 64 + mi * 16 + kq * 4;
            #pragma unroll
            for (int ni = 0; ni < 4; ++ni) {
                int c = o0 + wn * 64 + ni * 16 + ln;
                bfpack4 p;
                #pragma unroll
                for (int i = 0; i < 4; ++i) p.h[i] = (__bf16)acc[mi][ni][i];
                *(uint2*)(Y + ((size_t)b * CC + c) * LL + lb) = p.v;
            }
        }
    }
}

// ---------------------------------------------------------------- MFMA flash attention
// Q,K bf16 (B,L,C); V bf16 (B,C,L) (pre-transposed by GEMM mode 3).
// grid (L/64, H, B). outp fp32 (B,L,C) residual RMW. Pl stride 68 -> P-writes
// spread kq groups over banks {0,8,16,24} dw: 2 lanes/bank = free.
__global__ __launch_bounds__(256) void attn_mfma_kernel(
    const __bf16* __restrict__ qb, const __bf16* __restrict__ kb,
    const __bf16* __restrict__ vb, const int* __restrict__ maskp,
    float* __restrict__ outp)
{
    const int b = blockIdx.z, hh = blockIdx.y, ql0 = blockIdx.x * 64;
    const int tid = threadIdx.x, w = tid >> 6, lane = tid & 63;
    const int ln = lane & 15, kq = lane >> 4;

    __shared__ __bf16 Ql[64 * 72];   // [q][d]
    __shared__ __bf16 Kl[64 * 72];   // [m][d]
    __shared__ __bf16 Vl[64 * 72];   // [d][m]
    __shared__ __bf16 Pl[64 * 68];   // [q][m]  stride 68
    __shared__ float corrS[64], invS[64];

    const int co = hh * 64;
    const int sr = tid >> 3, sc8 = (tid & 7) * 8;   // staging: row, col-chunk

    {   // stage Q (rows already k-contiguous)
        #pragma unroll
        for (int j = 0; j < 2; ++j) {
            int r = sr + 32 * j;
            uint4 v = *(const uint4*)(qb + ((size_t)b * LL + ql0 + r) * CC + co + sc8);
            *(uint4*)(Ql + r * 72 + sc8) = v;
        }
    }

    float m_run[4], l_run[4];
    #pragma unroll
    for (int i = 0; i < 4; ++i) { m_run[i] = -INFINITY; l_run[i] = 0.f; }
    f32x4 oacc[4] = {};   // d = ni*16+kq*4+i, q = w*16+ln

    // prefetch tile 0
    uint4 kv0, kv1, vv0, vv1;
    kv0 = *(const uint4*)(kb + ((size_t)b * LL + sr) * CC + co + sc8);
    kv1 = *(const uint4*)(kb + ((size_t)b * LL + sr + 32) * CC + co + sc8);
    vv0 = *(const uint4*)(vb + ((size_t)(b * CC + co + sr)) * LL + sc8);
    vv1 = *(const uint4*)(vb + ((size_t)(b * CC + co + sr + 32)) * LL + sc8);

    for (int m0 = 0; m0 < LL; m0 += 64) {
        __syncthreads();
        *(uint4*)(Kl + sr * 72 + sc8)        = kv0;
        *(uint4*)(Kl + (sr + 32) * 72 + sc8) = kv1;
        *(uint4*)(Vl + sr * 72 + sc8)        = vv0;
        *(uint4*)(Vl + (sr + 32) * 72 + sc8) = vv1;
        __syncthreads();
        {   // issue next tile's loads; overlap QK/softmax/PV
            int mn = (m0 + 64 < LL) ? m0 + 64 : m0;
            kv0 = *(const uint4*)(kb + ((size_t)b * LL + mn + sr) * CC + co + sc8);
            kv1 = *(const uint4*)(kb + ((size_t)b * LL + mn + sr + 32) * CC + co + sc8);
            vv0 = *(const uint4*)(vb + ((size_t)(b * CC + co + sr)) * LL + mn + sc8);
            vv1 = *(const uint4*)(vb + ((size_t)(b * CC + co + sr + 32)) * LL + mn + sc8);
        }

        // ---- QK^T: lane rows q=kq*4+i (within wave tile), cols m=ni*16+ln
        f32x4 s[4] = {};
        {
            short8 aq[2];
            #pragma unroll
            for (int c = 0; c < 2; ++c)
                aq[c] = *(const short8*)(Ql + (w * 16 + ln) * 72 + c * 32 + kq * 8);
            #pragma unroll
            for (int ni = 0; ni < 4; ++ni)
                #pragma unroll
                for (int c = 0; c < 2; ++c) {
                    short8 bk = *(const short8*)(Kl + (ni * 16 + ln) * 72 + c * 32 + kq * 8);
                    s[ni] = __builtin_amdgcn_mfma_f32_16x16x32_bf16(aq[c], bk, s[ni], 0, 0, 0);
                }
        }

        // ---- online softmax
        float mf[4];
        #pragma unroll
        for (int ni = 0; ni < 4; ++ni)
            mf[ni] = (float)maskp[b * LL + m0 + ni * 16 + ln];
        float rmax[4];
        #pragma unroll
        for (int i = 0; i < 4; ++i) {
            float t = -INFINITY;
            #pragma unroll
            for (int ni = 0; ni < 4; ++ni) {
                s[ni][i] += -1e30f * (1.0f - mf[ni]);
                t = fmaxf(t, s[ni][i]);
            }
            rmax[i] = t;
        }
        #pragma unroll
        for (int off = 1; off < 16; off <<= 1)
            #pragma unroll
            for (int i = 0; i < 4; ++i)
                rmax[i] = fmaxf(rmax[i], __shfl_xor(rmax[i], off));

        float corr[4], rsum[4];
        #pragma unroll
        for (int i = 0; i < 4; ++i) {
            float nm = fmaxf(m_run[i], rmax[i]);
            corr[i] = __expf(m_run[i] - nm);
            m_run[i] = nm;
            float ssum = 0.f;
            #pragma unroll
            for (int ni = 0; ni < 4; ++ni) {
                float p = __expf(s[ni][i] - nm);
                s[ni][i] = p;
                ssum += p;
            }
            rsum[i] = ssum;
        }
        #pragma unroll
        for (int off = 1; off < 16; off <<= 1)
            #pragma unroll
            for (int i = 0; i < 4; ++i)
                rsum[i] += __shfl_xor(rsum[i], off);
        #pragma unroll
        for (int i = 0; i < 4; ++i)
            l_run[i] = l_run[i] * corr[i] + rsum[i];

        if (ln == 0) {
            #pragma unroll
            for (int i = 0; i < 4; ++i) corrS[w * 16 + kq * 4 + i] = corr[i];
        }
        #pragma unroll
        for (int ni = 0; ni < 4; ++ni)
            #pragma unroll
            for (int i = 0; i < 4; ++i)
                Pl[(w * 16 + kq * 4 + i) * 68 + ni * 16 + ln] = (__bf16)s[ni][i];
        __syncthreads();

        // ---- PV: A = V^T rows d, B = P rows q -> D[d][q]
        float oc = corrS[w * 16 + ln];
        short8 bp[2];
        #pragma unroll
        for (int c = 0; c < 2; ++c)
            bp[c] = *(const short8*)(Pl + (w * 16 + ln) * 68 + c * 32 + kq * 8);
        #pragma unroll
        for (int ni = 0; ni < 4; ++ni) {
            #pragma unroll
            for (int i = 0; i < 4; ++i) oacc[ni][i] *= oc;
            #pragma unroll
            for (int c = 0; c < 2; ++c) {
                short8 av = *(const short8*)(Vl + (ni * 16 + ln) * 72 + c * 32 + kq * 8);
                oacc[ni] = __builtin_amdgcn_mfma_f32_16x16x32_bf16(av, bp[c], oacc[ni], 0, 0, 0);
            }
        }
    }

    if (ln == 0) {
        #pragma unroll
        for (int i = 0; i < 4; ++i) invS[w * 16 + kq * 4 + i] = 1.0f / l_run[i];
    }
    __syncthreads();
    float inv = invS[w * 16 + ln];
    int l = ql0 + w * 16 + ln;
    #pragma unroll
    for (int ni = 0; ni < 4; ++ni) {
        int c = co + ni * 16 + kq * 4;
        size_t idx = ((size_t)b * LL + l) * CC + c;
        float4 r4 = *(const float4*)(outp + idx);
        r4.x += oacc[ni][0] * inv;
        r4.y += oacc[ni][1] * inv;
        r4.z += oacc[ni][2] * inv;
        r4.w += oacc[ni][3] * inv;
        *(float4*)(outp + idx) = r4;
    }
}

// ---------------------------------------------------------------- launch
extern "C" void kernel_launch(void* const* d_in, const int* in_sizes, int n_in,
                              void* d_out, int out_size, void* d_ws, size_t ws_size,
                              hipStream_t stream)
{
    const float* inputx  = (const float*)d_in[0];
    const int*   mask    = (const int*)  d_in[1];
    const float* ncs     = (const float*)d_in[4];
    const float* ncb     = (const float*)d_in[5];
    const float* dw_w    = (const float*)d_in[6];
    const float* pw_w    = (const float*)d_in[7];
    const float* pw_b    = (const float*)d_in[8];
    const float* ln1_s   = (const float*)d_in[9];
    const float* ln1_b   = (const float*)d_in[10];
    const float* ln2_s   = (const float*)d_in[11];
    const float* ln2_b   = (const float*)d_in[12];
    const float* w_kv    = (const float*)d_in[13];
    const float* w_q     = (const float*)d_in[14];
    const float* ffn1_w  = (const float*)d_in[15];
    const float* ffn1_b  = (const float*)d_in[16];
    const float* ffn2_w  = (const float*)d_in[17];
    const float* ffn2_b  = (const float*)d_in[18];

    const size_t NT = (size_t)BB * CC * LL;
    float*  result = (float*)d_ws;                 // fp32 (B,L,C)
    __bf16* wsb  = (__bf16*)(result + NT);
    __bf16* hb   = wsb;                            // ln output (B,L,C)
    __bf16* xb   = wsb + NT;                       // dwconv out / ffn hidden
    __bf16* qbuf = wsb + 2 * NT;
    __bf16* kbuf = wsb + 3 * NT;
    __bf16* vbuf = wsb + 4 * NT;                   // (B,C,L)
    __bf16* wpw  = wsb + 5 * NT;                   // 4*C*C
    __bf16* wkv  = wpw + 4 * CC * CC;              // 2*C*C
    __bf16* wq   = wkv + 2 * CC * CC;
    __bf16* wf1  = wq + CC * CC;
    __bf16* wf2  = wf1 + CC * CC;
    __bf16* dwt  = wf2 + CC * CC;                  // 4*K*C

    dim3 blk(256);
    dim3 ggrid(LL / 128, CC / 128, BB);

    // weight prep
    f32_to_bf16_kernel<<<(4 * CC * CC) / 1024, blk, 0, stream>>>(pw_w, wpw, 4 * CC * CC);
    f32_to_bf16_kernel<<<(2 * CC * CC) / 1024, blk, 0, stream>>>(w_kv, wkv, 2 * CC * CC);
    f32_to_bf16_kernel<<<(CC * CC) / 1024, blk, 0, stream>>>(w_q, wq, CC * CC);
    f32_to_bf16_kernel<<<(CC * CC) / 1024, blk, 0, stream>>>(ffn1_w, wf1, CC * CC);
    f32_to_bf16_kernel<<<(CC * CC) / 1024, blk, 0, stream>>>(ffn2_w, wf2, CC * CC);
    dw_transpose_kernel<<<(NCONV * KW * CC + 255) / 256, blk, 0, stream>>>(dw_w, dwt);

    pos_enc_t_kernel<<<dim3(LL / 64, CC / 64, BB), blk, 0, stream>>>(inputx, result);

    for (int i = 0; i < NCONV; ++i) {
        ln_last_kernel<<<BB * LL / 4, blk, 0, stream>>>(result, ncs + i * CC, ncb + i * CC, hb);
        dwconv_last_kernel<<<BB * LL * 64 / 256, blk, 0, stream>>>(hb, dwt + i * KW * CC, xb);
        gemm_bf_kernel<<<ggrid, blk, 0, stream>>>(wpw + (size_t)i * CC * CC, xb, result,
                                                  pw_b + i * CC, nullptr, 0, 1, 1.0f);
    }

    // attention
    ln_last_kernel<<<BB * LL / 4, blk, 0, stream>>>(result, ln1_s, ln1_b, hb);
    gemm_bf_kernel<<<ggrid, blk, 0, stream>>>(wkv,           hb, kbuf, nullptr, nullptr, 1, 0, 1.0f);
    gemm_bf_kernel<<<ggrid, blk, 0, stream>>>(wkv + CC * CC, hb, vbuf, nullptr, nullptr, 3, 0, 1.0f);
    gemm_bf_kernel<<<ggrid, blk, 0, stream>>>(wq,            hb, qbuf, nullptr, nullptr, 1, 0, 0.125f);
    attn_mfma_kernel<<<dim3(LL / 64, NH, BB), blk, 0, stream>>>(qbuf, kbuf, vbuf, mask, result);

    // ffn
    ln_last_kernel<<<BB * LL / 4, blk, 0, stream>>>(result, ln2_s, ln2_b, hb);
    gemm_bf_kernel<<<ggrid, blk, 0, stream>>>(wf1, hb, xb, ffn1_b, nullptr, 1, 1, 1.0f);
    gemm_bf_kernel<<<ggrid, blk, 0, stream>>>(wf2, xb, d_out, ffn2_b, result, 2, 0, 1.0f);
}